// Round 9
// baseline (12507.053 us; speedup 1.0000x reference)
//
#include <hip/hip_runtime.h>
#include <math.h>

#define HD 64
#define DATT 16
#define NCIN 3
#define NCOUT 2
#define HH 24
#define WW 48
#define SS (HH*WW)          // 1152
#define NB 16
#define TSTEPS 37
#define INPUT_FRAMES 12

#define PR 26
#define PC 52
#define PHW (PR*PC)         // 1352

// ---------------- workspace layout (floats) ----------------
#define OFF_H     0                      // 16*64*1352 = 1384448 (padded)
#define OFF_C     1384448                // 16*64*1152 (unpadded)
#define OFF_M     2564096                // 16*64*1152 (unpadded)
#define OFF_FEED  3743744                // 16*3*1352 (padded)
#define OFF_Z     3808640                // 16*16*1352 (padded)
#define ZERO_END  4154752                // everything above zeroed each launch
#define OFF_COMB  4154752                // 16*256*1152 = 4718592
#define OFF_QKV   4154752                // aliases comb (dead after lstm gates)
#define OFF_MKV   5039488                // qkv + 884736
#define OFF_IOG   8873344                // comb + 4718592
#define OFF_W2G   12412288               // 32*72*9*8 = 165888
#define OFF_W3G   12578176               // 24*80*9*8 = 138240
// end = 12716416 floats = 50.9 MB

__device__ __forceinline__ float sigmoidf_(float x) {
    return 1.0f / (1.0f + __expf(-x));
}

__global__ void k_zero(float* __restrict__ p, int n4) {
    int i = blockIdx.x * blockDim.x + threadIdx.x;
    if (i < n4) ((float4*)p)[i] = make_float4(0.f, 0.f, 0.f, 0.f);
}

// ---------------- weight reorder: conv_w -> w2g [ocg(32)][c(72)][kt(9)][ocl(8)] ----------------
__global__ void k_prep_w2g(const float* __restrict__ cw, float* __restrict__ w2g) {
    int idx = blockIdx.x * blockDim.x + threadIdx.x;
    if (idx >= 165888) return;
    int ocl = idx & 7;
    int kt  = (idx >> 3) % 9;
    int c   = (idx / 72) % 72;
    int ocg = idx / 5184;
    w2g[idx] = (c < 67) ? cw[(ocg * 8 + ocl) * 603 + c * 9 + kt] : 0.f;
}

// ---------------- weight reorder: o_w -> w3g [ocg(24)][c(80)][kt(9)][ocl(8)] ----------------
__global__ void k_prep_w3g(const float* __restrict__ ow, float* __restrict__ w3g) {
    int idx = blockIdx.x * blockDim.x + threadIdx.x;
    if (idx >= 138240) return;
    int ocl = idx & 7;
    int kt  = (idx >> 3) % 9;
    int c   = (idx / 72) % 80;
    int ocg = idx / 5760;
    w3g[idx] = ow[(ocg * 8 + ocl) * 720 + c * 9 + kt];
}

// ---------------- initial feed (t=0, always from x) ----------------
__global__ void k_feed0(const float* __restrict__ x, float* __restrict__ feed) {
    int i = blockIdx.x * blockDim.x + threadIdx.x;
    if (i >= NB * 3 * SS) return;
    int s = i % SS;
    int ch = (i / SS) % 3;
    int n = i / (3 * SS);
    int y = s / WW, xx = s % WW;
    float v = x[(((size_t)(n * TSTEPS + 0) * HH + y) * WW + xx) * NCIN + ch];
    feed[((size_t)(n * 3 + ch) * PR + (y + 1)) * PC + (xx + 1)] = v;
}

// ---------------- generic 3x3 conv, pad=1, fp32, padded inputs ----------------
// TWO oc-groups (16 oc) per block (r8); LDS DOUBLE-BUFFERED: 1 barrier/chunk.
// grid: (48, OC/16); block 192 = 24 col-groups (2 px) x 8 rows
__global__ __launch_bounds__(192) void k_conv3x3(
    const float* __restrict__ in1, int C1,
    const float* __restrict__ in2, int C2,
    const float* __restrict__ w, const float* __restrict__ b,
    float* __restrict__ out, int OC)
{
    __shared__ __align__(16) float lds_patch[2][8 * 520];   // 33.3 KB

    const int bx = blockIdx.x;
    const int n = bx / 3, tile = bx % 3;
    const int ocp = blockIdx.y;                 // oc-pair index
    const int C = C1 + C2;
    const int nchunk = (C + 7) / 8;
    const int tid = threadIdx.x;
    const int y0 = tile * 8;

    const int wgsz = nchunk * 8 * 72;
    const float* wg0 = w + (size_t)(ocp * 2) * wgsz;
    const float* wg1 = wg0 + wgsz;

    const float4* in1_4 = (const float4*)(in1 + (size_t)n * C1 * PHW);
    const float4* in2_4 = (const float4*)(in2 + (size_t)n * C2 * PHW);

    float4 pf[6];
    auto load_chunk = [&](int chunk) {
#pragma unroll
        for (int k = 0; k < 6; ++k) {
            int i = tid + 192 * k;
            if (i < 1040) {
                int c_l = i / 130;
                int rem = i - c_l * 130;
                int c = chunk * 8 + c_l;
                float4 v = make_float4(0.f, 0.f, 0.f, 0.f);
                if (c < C) {
                    v = (c < C1) ? in1_4[(c * PR + y0) * 13 + rem]
                                 : in2_4[((c - C1) * PR + y0) * 13 + rem];
                }
                pf[k] = v;
            }
        }
    };

    const int cg = tid % 24;
    const int ty = tid / 24;
    const int x0 = cg * 2;
    const int y_out = y0 + ty;

    float acc[32];
#pragma unroll
    for (int j = 0; j < 32; ++j) acc[j] = 0.f;

    load_chunk(0);
    for (int chunk = 0; chunk < nchunk; ++chunk) {
        float* buf = lds_patch[chunk & 1];
        // store prefetched chunk into its buffer (safe: all waves passed the
        // previous chunk's barrier, so no one still reads this buffer)
#pragma unroll
        for (int k = 0; k < 6; ++k) {
            int i = tid + 192 * k;
            if (i < 1040) ((float4*)buf)[i] = pf[k];
        }
        if (chunk + 1 < nchunk) load_chunk(chunk + 1);
        __syncthreads();    // single barrier: stores visible before compute

        for (int icl = 0; icl < 8; ++icl) {
            const int c = chunk * 8 + icl;
            const float* wb0 = wg0 + c * 72;    // block-uniform
            const float* wb1 = wg1 + c * 72;
            const float* pr = &buf[icl * 520 + ty * PC + x0];
#pragma unroll
            for (int ky = 0; ky < 3; ++ky) {
                const float* r = pr + ky * PC;
                float i0 = r[0], i1 = r[1], i2 = r[2], i3 = r[3];
                const float* wk0 = wb0 + ky * 24;
                const float* wk1 = wb1 + ky * 24;
#pragma unroll
                for (int kx = 0; kx < 3; ++kx) {
                    float va = (kx == 0) ? i0 : ((kx == 1) ? i1 : i2);
                    float vb = (kx == 0) ? i1 : ((kx == 1) ? i2 : i3);
                    const float4 wa0  = *(const float4*)(wk0 + kx * 8);
                    const float4 wb40 = *(const float4*)(wk0 + kx * 8 + 4);
                    const float4 wa1  = *(const float4*)(wk1 + kx * 8);
                    const float4 wb41 = *(const float4*)(wk1 + kx * 8 + 4);
                    acc[0]  += va * wa0.x;  acc[1]  += va * wa0.y;
                    acc[2]  += va * wa0.z;  acc[3]  += va * wa0.w;
                    acc[4]  += va * wb40.x; acc[5]  += va * wb40.y;
                    acc[6]  += va * wb40.z; acc[7]  += va * wb40.w;
                    acc[8]  += vb * wa0.x;  acc[9]  += vb * wa0.y;
                    acc[10] += vb * wa0.z;  acc[11] += vb * wa0.w;
                    acc[12] += vb * wb40.x; acc[13] += vb * wb40.y;
                    acc[14] += vb * wb40.z; acc[15] += vb * wb40.w;
                    acc[16] += va * wa1.x;  acc[17] += va * wa1.y;
                    acc[18] += va * wa1.z;  acc[19] += va * wa1.w;
                    acc[20] += va * wb41.x; acc[21] += va * wb41.y;
                    acc[22] += va * wb41.z; acc[23] += va * wb41.w;
                    acc[24] += vb * wa1.x;  acc[25] += vb * wa1.y;
                    acc[26] += vb * wa1.z;  acc[27] += vb * wa1.w;
                    acc[28] += vb * wb41.x; acc[29] += vb * wb41.y;
                    acc[30] += vb * wb41.z; acc[31] += vb * wb41.w;
                }
            }
        }
        __syncthreads();    // all done reading buf before it is overwritten
    }

#pragma unroll
    for (int j = 0; j < 8; ++j) {
        int oc0 = ocp * 16 + j;
        int oc1 = ocp * 16 + 8 + j;
        float bv0 = b[oc0];
        float bv1 = b[oc1];
        float2 o0 = make_float2(acc[j] + bv0, acc[8 + j] + bv0);
        float2 o1 = make_float2(acc[16 + j] + bv1, acc[24 + j] + bv1);
        *(float2*)&out[((n * OC + oc0) * HH + y_out) * WW + x0] = o0;
        *(float2*)&out[((n * OC + oc1) * HH + y_out) * WW + x0] = o1;
    }
}

// ---------------- ConvLSTM gates (h written padded) ----------------
__global__ void k_lstm_gates(const float* __restrict__ comb, float* __restrict__ c,
                             float* __restrict__ h) {
    int i = blockIdx.x * blockDim.x + threadIdx.x;
    if (i >= NB * HD * SS) return;
    int s = i % SS;
    int ch = (i / SS) % HD;
    int n = i / (HD * SS);
    const float* cb = comb + (size_t)n * 4 * HD * SS;
    float ci = cb[(ch) * SS + s];
    float cf = cb[(ch + HD) * SS + s];
    float co = cb[(ch + 2 * HD) * SS + s];
    float cg = cb[(ch + 3 * HD) * SS + s];
    float ig = sigmoidf_(ci);
    float fg = sigmoidf_(cf);
    float og = sigmoidf_(co);
    float gg = tanhf(cg);
    float cn = fg * c[i] + ig * gg;
    c[i] = cn;
    int y = s / WW, x = s % WW;
    h[((size_t)(n * HD + ch) * PR + (y + 1)) * PC + (x + 1)] = og * tanhf(cn);
}

// ---------------- 1x1 q/k/v + mk/mv projections (r5-verbatim, 10 groups x 8ch) ----------------
__global__ __launch_bounds__(256) void k_qkv(
    const float* __restrict__ h, const float* __restrict__ m,
    const float* __restrict__ hw, const float* __restrict__ hb,
    const float* __restrict__ mw, const float* __restrict__ mb,
    float* __restrict__ qkv, float* __restrict__ mkv) {
    __shared__ float lw[512];
    __shared__ float lb[8];
    const int g = blockIdx.y;
    const int tid = threadIdx.x;
    const float* wsrc = (g < 6) ? (hw + g * 512) : (mw + (g - 6) * 512);
    const float* bsrc = (g < 6) ? (hb + g * 8) : (mb + (g - 6) * 8);
    for (int i = tid; i < 512; i += 256) lw[i] = wsrc[i];
    if (tid < 8) lb[tid] = bsrc[tid];
    __syncthreads();

    int idx = blockIdx.x * 256 + tid;
    int s = idx % SS;
    int n = idx / SS;
    int y = s / WW, x = s % WW;

    float reg[HD];
    if (g < 6) {
        const float* src = h + (size_t)n * HD * PHW + (y + 1) * PC + (x + 1);
#pragma unroll
        for (int ic = 0; ic < HD; ++ic) reg[ic] = src[ic * PHW];
    } else {
        const float* src = m + (size_t)n * HD * SS + s;
#pragma unroll
        for (int ic = 0; ic < HD; ++ic) reg[ic] = src[ic * SS];
    }

    float* dst = (g < 6) ? &qkv[((size_t)n * SS + s) * 48 + g * 8]
                         : &mkv[((size_t)n * SS + s) * 32 + (g - 6) * 8];
#pragma unroll
    for (int j = 0; j < 8; ++j) {
        const float* wr = &lw[j * HD];
        float a = lb[j];
#pragma unroll
        for (int ic = 0; ic < HD; ++ic) a += reg[ic] * wr[ic];
        dst[j] = a;
    }
}

#define LOAD16(dst, srcp) do {                       \
    float4 _a = ((const float4*)(srcp))[0];          \
    float4 _b = ((const float4*)(srcp))[1];          \
    float4 _c = ((const float4*)(srcp))[2];          \
    float4 _d = ((const float4*)(srcp))[3];          \
    dst[0]=_a.x; dst[1]=_a.y; dst[2]=_a.z; dst[3]=_a.w;   \
    dst[4]=_b.x; dst[5]=_b.y; dst[6]=_b.z; dst[7]=_b.w;   \
    dst[8]=_c.x; dst[9]=_c.y; dst[10]=_c.z; dst[11]=_c.w; \
    dst[12]=_d.x; dst[13]=_d.y; dst[14]=_d.z; dst[15]=_d.w; } while(0)

// ---------------- dual spatial attention + z 1x1 (r7 + register tile prefetch) ----------------
// block 256 = 16 row-threads (2 rows each) x 16 t-partials; grid (36, 16)
#define TSTRIDE 68
__global__ __launch_bounds__(256) void k_attn(
    const float* __restrict__ qkv, const float* __restrict__ mkv,
    const float* __restrict__ zw, const float* __restrict__ zb,
    float* __restrict__ Z)
{
    __shared__ __align__(16) float smem[144 * TSTRIDE];  // 38.3 KB
    const int n = blockIdx.y;
    const int tid = threadIdx.x;
    const int rowthr = tid >> 4;    // 0..15
    const int part = tid & 15;      // 0..15 (== lane & 15)
    const int s0 = blockIdx.x * 32 + rowthr * 2;

    float q0[16], q1[16];
    LOAD16(q0, &qkv[((size_t)n * SS + s0) * 48]);
    LOAD16(q1, &qkv[((size_t)n * SS + s0 + 1) * 48]);

    float lh0 = 0.f, lh1 = 0.f, lm0 = 0.f, lm1 = 0.f;
    float oh0[16], oh1[16], om0[16], om1[16];
#pragma unroll
    for (int j = 0; j < 16; ++j) { oh0[j] = 0.f; oh1[j] = 0.f; om0[j] = 0.f; om1[j] = 0.f; }

    const float4* qkv4 = (const float4*)qkv + (size_t)n * SS * 12;
    const float4* mkv4 = (const float4*)mkv + (size_t)n * SS * 8;

    // register prefetch of a KV tile (9 float4/thread)
    float4 pre[9];
    auto prefetch = [&](int tile) {
#pragma unroll
        for (int k = 0; k < 9; ++k) {
            int j = tid + 256 * k;
            int t_loc = j >> 4, f = j & 15;
            int t = tile * 144 + t_loc;
            pre[k] = (f < 8) ? qkv4[t * 12 + 4 + f] : mkv4[t * 8 + (f - 8)];
        }
    };

    prefetch(0);
    for (int tile = 0; tile < 8; ++tile) {
        __syncthreads();    // all waves done reading smem (previous tile)
#pragma unroll
        for (int k = 0; k < 9; ++k) {
            int j = tid + 256 * k;
            int t_loc = j >> 4, f = j & 15;
            *(float4*)&smem[t_loc * TSTRIDE + f * 4] = pre[k];
        }
        if (tile + 1 < 8) prefetch(tile + 1);   // loads overlap compute below
        __syncthreads();

        const int t0 = part * 9;
        for (int tl = t0; tl < t0 + 9; ++tl) {
            const float* kvb = &smem[tl * TSTRIDE];
            float kk[16], vv[16];
            LOAD16(kk, kvb);
            float d0 = 0.f, d1 = 0.f;
#pragma unroll
            for (int j = 0; j < 16; ++j) { d0 += q0[j] * kk[j]; d1 += q1[j] * kk[j]; }
            float e0 = __expf(d0 * 0.25f), e1 = __expf(d1 * 0.25f);
            lh0 += e0; lh1 += e1;
            LOAD16(vv, kvb + 16);
#pragma unroll
            for (int j = 0; j < 16; ++j) { oh0[j] += e0 * vv[j]; oh1[j] += e1 * vv[j]; }
            LOAD16(kk, kvb + 32);
            float f0 = 0.f, f1 = 0.f;
#pragma unroll
            for (int j = 0; j < 16; ++j) { f0 += q0[j] * kk[j]; f1 += q1[j] * kk[j]; }
            float g0 = __expf(f0 * 0.25f), g1 = __expf(f1 * 0.25f);
            lm0 += g0; lm1 += g1;
            LOAD16(vv, kvb + 48);
#pragma unroll
            for (int j = 0; j < 16; ++j) { om0[j] += g0 * vv[j]; om1[j] += g1 * vv[j]; }
        }
    }

#pragma unroll
    for (int mask = 1; mask <= 8; mask <<= 1) {
        lh0 += __shfl_xor(lh0, mask, 16);
        lh1 += __shfl_xor(lh1, mask, 16);
        lm0 += __shfl_xor(lm0, mask, 16);
        lm1 += __shfl_xor(lm1, mask, 16);
#pragma unroll
        for (int j = 0; j < 16; ++j) {
            oh0[j] += __shfl_xor(oh0[j], mask, 16);
            oh1[j] += __shfl_xor(oh1[j], mask, 16);
            om0[j] += __shfl_xor(om0[j], mask, 16);
            om1[j] += __shfl_xor(om1[j], mask, 16);
        }
    }

    const int zc = part;
    const float* zr = &zw[zc * 32];
    float zrh[16], zrm[16];
    LOAD16(zrh, zr);
    LOAD16(zrm, zr + 16);
    float zbv = zb[zc];
    float ilh0 = 1.f / lh0, ilh1 = 1.f / lh1;
    float ilm0 = 1.f / lm0, ilm1 = 1.f / lm1;
    float a0 = zbv, a1 = zbv;
#pragma unroll
    for (int j = 0; j < 16; ++j) {
        a0 += zrh[j] * (oh0[j] * ilh0) + zrm[j] * (om0[j] * ilm0);
        a1 += zrh[j] * (oh1[j] * ilh1) + zrm[j] * (om1[j] * ilm1);
    }
    {
        int y0_ = s0 / WW, x0_ = s0 % WW;
        Z[((size_t)(n * DATT + zc) * PR + y0_ + 1) * PC + x0_ + 1] = a0;
        int y1_ = (s0 + 1) / WW, x1_ = (s0 + 1) % WW;
        Z[((size_t)(n * DATT + zc) * PR + y1_ + 1) * PC + x1_ + 1] = a1;
    }
}

// ---------------- SA memory gates (h written padded) ----------------
__global__ void k_sa_gates(const float* __restrict__ iog, float* __restrict__ m,
                           float* __restrict__ h) {
    int i = blockIdx.x * blockDim.x + threadIdx.x;
    if (i >= NB * HD * SS) return;
    int s = i % SS;
    int ch = (i / SS) % HD;
    int n = i / (HD * SS);
    const float* ib = iog + (size_t)n * 3 * HD * SS;
    float si = ib[ch * SS + s];
    float sg = ib[(HD + ch) * SS + s];
    float so = ib[(2 * HD + ch) * SS + s];
    si = sigmoidf_(si);
    sg = tanhf(sg);
    float mn = si * sg + (1.f - si) * m[i];
    m[i] = mn;
    int y = s / WW, x = s % WW;
    h[((size_t)(n * HD + ch) * PR + (y + 1)) * PC + (x + 1)] = sigmoidf_(so) * mn;
}

// ---------------- out 1x1 (64->2) + next-step feed, fused ----------------
__global__ void k_out_feed(const float* __restrict__ h, const float* __restrict__ ow,
                           const float* __restrict__ ob, const float* __restrict__ x,
                           float* __restrict__ outbuf, float* __restrict__ feed, int t) {
    int idx = blockIdx.x * 256 + threadIdx.x;
    if (idx >= NB * SS) return;
    int s = idx % SS;
    int n = idx / SS;
    int y = s / WW, xx = s % WW;
    const float* src = h + (size_t)n * HD * PHW + (y + 1) * PC + (xx + 1);
    float o0 = ob[0], o1 = ob[1];
#pragma unroll
    for (int ic = 0; ic < HD; ++ic) {
        float r = src[ic * PHW];
        o0 += r * ow[ic];
        o1 += r * ow[HD + ic];
    }
    outbuf[(((size_t)n * TSTEPS + t) * NCOUT + 0) * SS + s] = o0;
    outbuf[(((size_t)n * TSTEPS + t) * NCOUT + 1) * SS + s] = o1;

    if (t + 1 < TSTEPS) {
        int t1 = t + 1;
        const float* xp = &x[(((size_t)(n * TSTEPS + t1) * HH + y) * WW + xx) * NCIN];
        float f0, f1, f2 = xp[2];
        if (t1 < INPUT_FRAMES) { f0 = xp[0]; f1 = xp[1]; }
        else { f0 = o0; f1 = o1; }
        size_t fb = ((size_t)(n * 3 + 0) * PR + y + 1) * PC + xx + 1;
        feed[fb] = f0;
        feed[fb + PHW] = f1;
        feed[fb + 2 * (size_t)PHW] = f2;
    }
}

// ---------------- nino prediction ----------------
__global__ void k_nino(const float* __restrict__ outbuf, float* __restrict__ pred) {
    int tidx = threadIdx.x;
    if (tidx >= 16 * 24) return;
    int j = tidx % 24;
    int n = tidx / 24;
    float acc = 0.f;
    for (int f = j; f < j + 3; ++f) {
        int t = 11 + f;
        const float* p = &outbuf[(((size_t)n * TSTEPS + t) * NCOUT + 0) * SS];
        float sloc = 0.f;
        for (int y = 10; y <= 12; ++y)
            for (int x = 19; x <= 29; ++x)
                sloc += p[y * WW + x];
        acc += sloc * (1.f / 33.f);
    }
    pred[n * 24 + j] = acc * (1.f / 3.f);
}

extern "C" void kernel_launch(void* const* d_in, const int* in_sizes, int n_in,
                              void* d_out, int out_size, void* d_ws, size_t ws_size,
                              hipStream_t stream) {
    const float* x      = (const float*)d_in[0];
    const float* conv_w = (const float*)d_in[1];
    const float* conv_b = (const float*)d_in[2];
    const float* h_w    = (const float*)d_in[3];
    const float* h_b    = (const float*)d_in[4];
    const float* m_w    = (const float*)d_in[5];
    const float* m_b    = (const float*)d_in[6];
    const float* z_w    = (const float*)d_in[7];
    const float* z_b    = (const float*)d_in[8];
    const float* o_w    = (const float*)d_in[9];
    const float* o_b    = (const float*)d_in[10];
    const float* out_w  = (const float*)d_in[11];
    const float* out_b  = (const float*)d_in[12];

    float* ws   = (float*)d_ws;
    float* h    = ws + OFF_H;
    float* c    = ws + OFF_C;
    float* m    = ws + OFF_M;
    float* feed = ws + OFF_FEED;
    float* comb = ws + OFF_COMB;
    float* qkv  = ws + OFF_QKV;
    float* mkv  = ws + OFF_MKV;
    float* Zb   = ws + OFF_Z;
    float* iog  = ws + OFF_IOG;
    float* w2g  = ws + OFF_W2G;
    float* w3g  = ws + OFF_W3G;
    float* outp = (float*)d_out;

    k_zero<<<4058, 256, 0, stream>>>(ws, 1038688);
    k_prep_w2g<<<648, 256, 0, stream>>>(conv_w, w2g);
    k_prep_w3g<<<540, 256, 0, stream>>>(o_w, w3g);
    k_feed0<<<216, 256, 0, stream>>>(x, feed);

    for (int t = 0; t < TSTEPS; ++t) {
        k_conv3x3<<<dim3(48, 16), 192, 0, stream>>>(feed, 3, h, HD, w2g, conv_b,
                                                    comb, 4 * HD);
        k_lstm_gates<<<4608, 256, 0, stream>>>(comb, c, h);
        k_qkv<<<dim3(72, 10), 256, 0, stream>>>(h, m, h_w, h_b, m_w, m_b, qkv, mkv);
        k_attn<<<dim3(36, 16), 256, 0, stream>>>(qkv, mkv, z_w, z_b, Zb);
        k_conv3x3<<<dim3(48, 12), 192, 0, stream>>>(Zb, DATT, h, HD, w3g, o_b,
                                                    iog, 3 * HD);
        k_sa_gates<<<4608, 256, 0, stream>>>(iog, m, h);
        k_out_feed<<<72, 256, 0, stream>>>(h, out_w, out_b, x, outp, feed, t);
    }
    k_nino<<<1, 384, 0, stream>>>(outp, outp + (size_t)NB * TSTEPS * NCOUT * SS);
}

// Round 10
// 12112.304 us; speedup vs baseline: 1.0326x; 1.0326x over previous
//
#include <hip/hip_runtime.h>
#include <math.h>

#define HD 64
#define DATT 16
#define NCIN 3
#define NCOUT 2
#define HH 24
#define WW 48
#define SS (HH*WW)          // 1152
#define NB 16
#define TSTEPS 37
#define INPUT_FRAMES 12

#define PR 26
#define PC 52
#define PHW (PR*PC)         // 1352

// ---------------- workspace layout (floats) ----------------
#define OFF_H     0                      // 16*64*1352 = 1384448 (padded)
#define OFF_C     1384448                // 16*64*1152 (unpadded)
#define OFF_M     2564096                // 16*64*1152 (unpadded)
#define OFF_FEED  3743744                // 16*3*1352 (padded)
#define OFF_Z     3808640                // 16*16*1352 (padded)
#define ZERO_END  4154752                // everything above zeroed each launch
#define OFF_COMB  4154752                // 16*256*1152 = 4718592
#define OFF_QKV   4154752                // aliases comb (dead after lstm gates)
#define OFF_MKV   5039488                // qkv + 884736
#define OFF_IOG   8873344                // comb + 4718592
#define OFF_W2G   12412288               // 32*72*9*8 = 165888
#define OFF_W3G   12578176               // 24*80*9*8 = 138240
// end = 12716416 floats = 50.9 MB

__device__ __forceinline__ float sigmoidf_(float x) {
    return 1.0f / (1.0f + __expf(-x));
}

__global__ void k_zero(float* __restrict__ p, int n4) {
    int i = blockIdx.x * blockDim.x + threadIdx.x;
    if (i < n4) ((float4*)p)[i] = make_float4(0.f, 0.f, 0.f, 0.f);
}

// ---------------- weight reorder: conv_w -> w2g [ocg(32)][c(72)][kt(9)][ocl(8)] ----------------
__global__ void k_prep_w2g(const float* __restrict__ cw, float* __restrict__ w2g) {
    int idx = blockIdx.x * blockDim.x + threadIdx.x;
    if (idx >= 165888) return;
    int ocl = idx & 7;
    int kt  = (idx >> 3) % 9;
    int c   = (idx / 72) % 72;
    int ocg = idx / 5184;
    w2g[idx] = (c < 67) ? cw[(ocg * 8 + ocl) * 603 + c * 9 + kt] : 0.f;
}

// ---------------- weight reorder: o_w -> w3g [ocg(24)][c(80)][kt(9)][ocl(8)] ----------------
__global__ void k_prep_w3g(const float* __restrict__ ow, float* __restrict__ w3g) {
    int idx = blockIdx.x * blockDim.x + threadIdx.x;
    if (idx >= 138240) return;
    int ocl = idx & 7;
    int kt  = (idx >> 3) % 9;
    int c   = (idx / 72) % 80;
    int ocg = idx / 5760;
    w3g[idx] = ow[(ocg * 8 + ocl) * 720 + c * 9 + kt];
}

// ---------------- initial feed (t=0, always from x) ----------------
__global__ void k_feed0(const float* __restrict__ x, float* __restrict__ feed) {
    int i = blockIdx.x * blockDim.x + threadIdx.x;
    if (i >= NB * 3 * SS) return;
    int s = i % SS;
    int ch = (i / SS) % 3;
    int n = i / (3 * SS);
    int y = s / WW, xx = s % WW;
    float v = x[(((size_t)(n * TSTEPS + 0) * HH + y) * WW + xx) * NCIN + ch];
    feed[((size_t)(n * 3 + ch) * PR + (y + 1)) * PC + (xx + 1)] = v;
}

// ---------------- generic 3x3 conv, pad=1, fp32, padded inputs (r8-verbatim) ----------------
// TWO oc-groups (16 oc) per block; single LDS buffer.
// grid: (48, OC/16); block 192 = 24 col-groups (2 px) x 8 rows
__global__ __launch_bounds__(192) void k_conv3x3(
    const float* __restrict__ in1, int C1,
    const float* __restrict__ in2, int C2,
    const float* __restrict__ w, const float* __restrict__ b,
    float* __restrict__ out, int OC)
{
    __shared__ __align__(16) float lds_patch[8 * 520];

    const int bx = blockIdx.x;
    const int n = bx / 3, tile = bx % 3;
    const int ocp = blockIdx.y;                 // oc-pair index
    const int C = C1 + C2;
    const int nchunk = (C + 7) / 8;
    const int tid = threadIdx.x;
    const int y0 = tile * 8;

    const int wgsz = nchunk * 8 * 72;
    const float* wg0 = w + (size_t)(ocp * 2) * wgsz;
    const float* wg1 = wg0 + wgsz;

    const float4* in1_4 = (const float4*)(in1 + (size_t)n * C1 * PHW);
    const float4* in2_4 = (const float4*)(in2 + (size_t)n * C2 * PHW);

    float4 pf[6];
    auto load_chunk = [&](int chunk) {
#pragma unroll
        for (int k = 0; k < 6; ++k) {
            int i = tid + 192 * k;
            if (i < 1040) {
                int c_l = i / 130;
                int rem = i - c_l * 130;
                int c = chunk * 8 + c_l;
                float4 v = make_float4(0.f, 0.f, 0.f, 0.f);
                if (c < C) {
                    v = (c < C1) ? in1_4[(c * PR + y0) * 13 + rem]
                                 : in2_4[((c - C1) * PR + y0) * 13 + rem];
                }
                pf[k] = v;
            }
        }
    };

    const int cg = tid % 24;
    const int ty = tid / 24;
    const int x0 = cg * 2;
    const int y_out = y0 + ty;

    float acc[32];
#pragma unroll
    for (int j = 0; j < 32; ++j) acc[j] = 0.f;

    load_chunk(0);
    for (int chunk = 0; chunk < nchunk; ++chunk) {
        __syncthreads();
#pragma unroll
        for (int k = 0; k < 6; ++k) {
            int i = tid + 192 * k;
            if (i < 1040) ((float4*)lds_patch)[i] = pf[k];
        }
        if (chunk + 1 < nchunk) load_chunk(chunk + 1);
        __syncthreads();

        for (int icl = 0; icl < 8; ++icl) {
            const int c = chunk * 8 + icl;
            const float* wb0 = wg0 + c * 72;    // block-uniform
            const float* wb1 = wg1 + c * 72;
            const float* pr = &lds_patch[icl * 520 + ty * PC + x0];
#pragma unroll
            for (int ky = 0; ky < 3; ++ky) {
                const float* r = pr + ky * PC;
                float i0 = r[0], i1 = r[1], i2 = r[2], i3 = r[3];
                const float* wk0 = wb0 + ky * 24;
                const float* wk1 = wb1 + ky * 24;
#pragma unroll
                for (int kx = 0; kx < 3; ++kx) {
                    float va = (kx == 0) ? i0 : ((kx == 1) ? i1 : i2);
                    float vb = (kx == 0) ? i1 : ((kx == 1) ? i2 : i3);
                    const float4 wa0  = *(const float4*)(wk0 + kx * 8);
                    const float4 wb40 = *(const float4*)(wk0 + kx * 8 + 4);
                    const float4 wa1  = *(const float4*)(wk1 + kx * 8);
                    const float4 wb41 = *(const float4*)(wk1 + kx * 8 + 4);
                    acc[0]  += va * wa0.x;  acc[1]  += va * wa0.y;
                    acc[2]  += va * wa0.z;  acc[3]  += va * wa0.w;
                    acc[4]  += va * wb40.x; acc[5]  += va * wb40.y;
                    acc[6]  += va * wb40.z; acc[7]  += va * wb40.w;
                    acc[8]  += vb * wa0.x;  acc[9]  += vb * wa0.y;
                    acc[10] += vb * wa0.z;  acc[11] += vb * wa0.w;
                    acc[12] += vb * wb40.x; acc[13] += vb * wb40.y;
                    acc[14] += vb * wb40.z; acc[15] += vb * wb40.w;
                    acc[16] += va * wa1.x;  acc[17] += va * wa1.y;
                    acc[18] += va * wa1.z;  acc[19] += va * wa1.w;
                    acc[20] += va * wb41.x; acc[21] += va * wb41.y;
                    acc[22] += va * wb41.z; acc[23] += va * wb41.w;
                    acc[24] += vb * wa1.x;  acc[25] += vb * wa1.y;
                    acc[26] += vb * wa1.z;  acc[27] += vb * wa1.w;
                    acc[28] += vb * wb41.x; acc[29] += vb * wb41.y;
                    acc[30] += vb * wb41.z; acc[31] += vb * wb41.w;
                }
            }
        }
    }

#pragma unroll
    for (int j = 0; j < 8; ++j) {
        int oc0 = ocp * 16 + j;
        int oc1 = ocp * 16 + 8 + j;
        float bv0 = b[oc0];
        float bv1 = b[oc1];
        float2 o0 = make_float2(acc[j] + bv0, acc[8 + j] + bv0);
        float2 o1 = make_float2(acc[16 + j] + bv1, acc[24 + j] + bv1);
        *(float2*)&out[((n * OC + oc0) * HH + y_out) * WW + x0] = o0;
        *(float2*)&out[((n * OC + oc1) * HH + y_out) * WW + x0] = o1;
    }
}

// ---------------- ConvLSTM gates (h written padded) ----------------
__global__ void k_lstm_gates(const float* __restrict__ comb, float* __restrict__ c,
                             float* __restrict__ h) {
    int i = blockIdx.x * blockDim.x + threadIdx.x;
    if (i >= NB * HD * SS) return;
    int s = i % SS;
    int ch = (i / SS) % HD;
    int n = i / (HD * SS);
    const float* cb = comb + (size_t)n * 4 * HD * SS;
    float ci = cb[(ch) * SS + s];
    float cf = cb[(ch + HD) * SS + s];
    float co = cb[(ch + 2 * HD) * SS + s];
    float cg = cb[(ch + 3 * HD) * SS + s];
    float ig = sigmoidf_(ci);
    float fg = sigmoidf_(cf);
    float og = sigmoidf_(co);
    float gg = tanhf(cg);
    float cn = fg * c[i] + ig * gg;
    c[i] = cn;
    int y = s / WW, x = s % WW;
    h[((size_t)(n * HD + ch) * PR + (y + 1)) * PC + (x + 1)] = og * tanhf(cn);
}

// ---------------- 1x1 q/k/v + mk/mv projections (10 groups x 8ch) ----------------
__global__ __launch_bounds__(256) void k_qkv(
    const float* __restrict__ h, const float* __restrict__ m,
    const float* __restrict__ hw, const float* __restrict__ hb,
    const float* __restrict__ mw, const float* __restrict__ mb,
    float* __restrict__ qkv, float* __restrict__ mkv) {
    __shared__ float lw[512];
    __shared__ float lb[8];
    const int g = blockIdx.y;
    const int tid = threadIdx.x;
    const float* wsrc = (g < 6) ? (hw + g * 512) : (mw + (g - 6) * 512);
    const float* bsrc = (g < 6) ? (hb + g * 8) : (mb + (g - 6) * 8);
    for (int i = tid; i < 512; i += 256) lw[i] = wsrc[i];
    if (tid < 8) lb[tid] = bsrc[tid];
    __syncthreads();

    int idx = blockIdx.x * 256 + tid;
    int s = idx % SS;
    int n = idx / SS;
    int y = s / WW, x = s % WW;

    float reg[HD];
    if (g < 6) {
        const float* src = h + (size_t)n * HD * PHW + (y + 1) * PC + (x + 1);
#pragma unroll
        for (int ic = 0; ic < HD; ++ic) reg[ic] = src[ic * PHW];
    } else {
        const float* src = m + (size_t)n * HD * SS + s;
#pragma unroll
        for (int ic = 0; ic < HD; ++ic) reg[ic] = src[ic * SS];
    }

    float* dst = (g < 6) ? &qkv[((size_t)n * SS + s) * 48 + g * 8]
                         : &mkv[((size_t)n * SS + s) * 32 + (g - 6) * 8];
#pragma unroll
    for (int j = 0; j < 8; ++j) {
        const float* wr = &lw[j * HD];
        float a = lb[j];
#pragma unroll
        for (int ic = 0; ic < HD; ++ic) a += reg[ic] * wr[ic];
        dst[j] = a;
    }
}

#define LOAD16(dst, srcp) do {                       \
    float4 _a = ((const float4*)(srcp))[0];          \
    float4 _b = ((const float4*)(srcp))[1];          \
    float4 _c = ((const float4*)(srcp))[2];          \
    float4 _d = ((const float4*)(srcp))[3];          \
    dst[0]=_a.x; dst[1]=_a.y; dst[2]=_a.z; dst[3]=_a.w;   \
    dst[4]=_b.x; dst[5]=_b.y; dst[6]=_b.z; dst[7]=_b.w;   \
    dst[8]=_c.x; dst[9]=_c.y; dst[10]=_c.z; dst[11]=_c.w; \
    dst[12]=_d.x; dst[13]=_d.y; dst[14]=_d.z; dst[15]=_d.w; } while(0)

// ---------------- dual spatial attention + z 1x1 ----------------
// grid (48,16) = 768 blocks = exactly 3/CU (tail-free). block 192 =
// 12 row-threads (2 rows each => 24 rows) x 16 t-partials. No prefetch
// (r9: +36 VGPR -> 2 waves/SIMD cliff). No max-subtraction (scores bounded).
#define TSTRIDE 68
__global__ __launch_bounds__(192) void k_attn(
    const float* __restrict__ qkv, const float* __restrict__ mkv,
    const float* __restrict__ zw, const float* __restrict__ zb,
    float* __restrict__ Z)
{
    __shared__ __align__(16) float smem[144 * TSTRIDE];  // 38.3 KB; 3 blocks/CU ok
    const int n = blockIdx.y;
    const int tid = threadIdx.x;
    const int rowthr = tid >> 4;    // 0..11
    const int part = tid & 15;      // 0..15 (== lane & 15)
    const int s0 = blockIdx.x * 24 + rowthr * 2;

    float q0[16], q1[16];
    LOAD16(q0, &qkv[((size_t)n * SS + s0) * 48]);
    LOAD16(q1, &qkv[((size_t)n * SS + s0 + 1) * 48]);

    float lh0 = 0.f, lh1 = 0.f, lm0 = 0.f, lm1 = 0.f;
    float oh0[16], oh1[16], om0[16], om1[16];
#pragma unroll
    for (int j = 0; j < 16; ++j) { oh0[j] = 0.f; oh1[j] = 0.f; om0[j] = 0.f; om1[j] = 0.f; }

    const float4* qkv4 = (const float4*)qkv + (size_t)n * SS * 12;
    const float4* mkv4 = (const float4*)mkv + (size_t)n * SS * 8;

    for (int tile = 0; tile < 8; ++tile) {
        __syncthreads();
        // stage 144 t x 16 f4 = 2304 f4 ; 192 threads x 12 exact
#pragma unroll
        for (int k = 0; k < 12; ++k) {
            int j = tid + 192 * k;
            int t_loc = j >> 4, f = j & 15;
            int t = tile * 144 + t_loc;
            float4 v;
            if (f < 8) v = qkv4[t * 12 + 4 + f];
            else       v = mkv4[t * 8 + (f - 8)];
            *(float4*)&smem[t_loc * TSTRIDE + f * 4] = v;
        }
        __syncthreads();

        const int t0 = part * 9;
        for (int tl = t0; tl < t0 + 9; ++tl) {
            const float* kvb = &smem[tl * TSTRIDE];
            float kk[16], vv[16];
            LOAD16(kk, kvb);
            float d0 = 0.f, d1 = 0.f;
#pragma unroll
            for (int j = 0; j < 16; ++j) { d0 += q0[j] * kk[j]; d1 += q1[j] * kk[j]; }
            float e0 = __expf(d0 * 0.25f), e1 = __expf(d1 * 0.25f);
            lh0 += e0; lh1 += e1;
            LOAD16(vv, kvb + 16);
#pragma unroll
            for (int j = 0; j < 16; ++j) { oh0[j] += e0 * vv[j]; oh1[j] += e1 * vv[j]; }
            LOAD16(kk, kvb + 32);
            float f0 = 0.f, f1 = 0.f;
#pragma unroll
            for (int j = 0; j < 16; ++j) { f0 += q0[j] * kk[j]; f1 += q1[j] * kk[j]; }
            float g0 = __expf(f0 * 0.25f), g1 = __expf(f1 * 0.25f);
            lm0 += g0; lm1 += g1;
            LOAD16(vv, kvb + 48);
#pragma unroll
            for (int j = 0; j < 16; ++j) { om0[j] += g0 * vv[j]; om1[j] += g1 * vv[j]; }
        }
    }

    // butterfly all-reduce across the 16 partials (lane bits 0..3)
#pragma unroll
    for (int mask = 1; mask <= 8; mask <<= 1) {
        lh0 += __shfl_xor(lh0, mask, 16);
        lh1 += __shfl_xor(lh1, mask, 16);
        lm0 += __shfl_xor(lm0, mask, 16);
        lm1 += __shfl_xor(lm1, mask, 16);
#pragma unroll
        for (int j = 0; j < 16; ++j) {
            oh0[j] += __shfl_xor(oh0[j], mask, 16);
            oh1[j] += __shfl_xor(oh1[j], mask, 16);
            om0[j] += __shfl_xor(om0[j], mask, 16);
            om1[j] += __shfl_xor(om1[j], mask, 16);
        }
    }

    const int zc = part;
    const float* zr = &zw[zc * 32];
    float zrh[16], zrm[16];
    LOAD16(zrh, zr);
    LOAD16(zrm, zr + 16);
    float zbv = zb[zc];
    float ilh0 = 1.f / lh0, ilh1 = 1.f / lh1;
    float ilm0 = 1.f / lm0, ilm1 = 1.f / lm1;
    float a0 = zbv, a1 = zbv;
#pragma unroll
    for (int j = 0; j < 16; ++j) {
        a0 += zrh[j] * (oh0[j] * ilh0) + zrm[j] * (om0[j] * ilm0);
        a1 += zrh[j] * (oh1[j] * ilh1) + zrm[j] * (om1[j] * ilm1);
    }
    {
        int y0_ = s0 / WW, x0_ = s0 % WW;
        Z[((size_t)(n * DATT + zc) * PR + y0_ + 1) * PC + x0_ + 1] = a0;
        int y1_ = (s0 + 1) / WW, x1_ = (s0 + 1) % WW;
        Z[((size_t)(n * DATT + zc) * PR + y1_ + 1) * PC + x1_ + 1] = a1;
    }
}

// ---------------- SA memory gates (h written padded) ----------------
__global__ void k_sa_gates(const float* __restrict__ iog, float* __restrict__ m,
                           float* __restrict__ h) {
    int i = blockIdx.x * blockDim.x + threadIdx.x;
    if (i >= NB * HD * SS) return;
    int s = i % SS;
    int ch = (i / SS) % HD;
    int n = i / (HD * SS);
    const float* ib = iog + (size_t)n * 3 * HD * SS;
    float si = ib[ch * SS + s];
    float sg = ib[(HD + ch) * SS + s];
    float so = ib[(2 * HD + ch) * SS + s];
    si = sigmoidf_(si);
    sg = tanhf(sg);
    float mn = si * sg + (1.f - si) * m[i];
    m[i] = mn;
    int y = s / WW, x = s % WW;
    h[((size_t)(n * HD + ch) * PR + (y + 1)) * PC + (x + 1)] = sigmoidf_(so) * mn;
}

// ---------------- out 1x1 (64->2) + next-step feed, fused ----------------
__global__ void k_out_feed(const float* __restrict__ h, const float* __restrict__ ow,
                           const float* __restrict__ ob, const float* __restrict__ x,
                           float* __restrict__ outbuf, float* __restrict__ feed, int t) {
    int idx = blockIdx.x * 256 + threadIdx.x;
    if (idx >= NB * SS) return;
    int s = idx % SS;
    int n = idx / SS;
    int y = s / WW, xx = s % WW;
    const float* src = h + (size_t)n * HD * PHW + (y + 1) * PC + (xx + 1);
    float o0 = ob[0], o1 = ob[1];
#pragma unroll
    for (int ic = 0; ic < HD; ++ic) {
        float r = src[ic * PHW];
        o0 += r * ow[ic];
        o1 += r * ow[HD + ic];
    }
    outbuf[(((size_t)n * TSTEPS + t) * NCOUT + 0) * SS + s] = o0;
    outbuf[(((size_t)n * TSTEPS + t) * NCOUT + 1) * SS + s] = o1;

    if (t + 1 < TSTEPS) {
        int t1 = t + 1;
        const float* xp = &x[(((size_t)(n * TSTEPS + t1) * HH + y) * WW + xx) * NCIN];
        float f0, f1, f2 = xp[2];
        if (t1 < INPUT_FRAMES) { f0 = xp[0]; f1 = xp[1]; }
        else { f0 = o0; f1 = o1; }
        size_t fb = ((size_t)(n * 3 + 0) * PR + y + 1) * PC + xx + 1;
        feed[fb] = f0;
        feed[fb + PHW] = f1;
        feed[fb + 2 * (size_t)PHW] = f2;
    }
}

// ---------------- nino prediction ----------------
__global__ void k_nino(const float* __restrict__ outbuf, float* __restrict__ pred) {
    int tidx = threadIdx.x;
    if (tidx >= 16 * 24) return;
    int j = tidx % 24;
    int n = tidx / 24;
    float acc = 0.f;
    for (int f = j; f < j + 3; ++f) {
        int t = 11 + f;
        const float* p = &outbuf[(((size_t)n * TSTEPS + t) * NCOUT + 0) * SS];
        float sloc = 0.f;
        for (int y = 10; y <= 12; ++y)
            for (int x = 19; x <= 29; ++x)
                sloc += p[y * WW + x];
        acc += sloc * (1.f / 33.f);
    }
    pred[n * 24 + j] = acc * (1.f / 3.f);
}

extern "C" void kernel_launch(void* const* d_in, const int* in_sizes, int n_in,
                              void* d_out, int out_size, void* d_ws, size_t ws_size,
                              hipStream_t stream) {
    const float* x      = (const float*)d_in[0];
    const float* conv_w = (const float*)d_in[1];
    const float* conv_b = (const float*)d_in[2];
    const float* h_w    = (const float*)d_in[3];
    const float* h_b    = (const float*)d_in[4];
    const float* m_w    = (const float*)d_in[5];
    const float* m_b    = (const float*)d_in[6];
    const float* z_w    = (const float*)d_in[7];
    const float* z_b    = (const float*)d_in[8];
    const float* o_w    = (const float*)d_in[9];
    const float* o_b    = (const float*)d_in[10];
    const float* out_w  = (const float*)d_in[11];
    const float* out_b  = (const float*)d_in[12];

    float* ws   = (float*)d_ws;
    float* h    = ws + OFF_H;
    float* c    = ws + OFF_C;
    float* m    = ws + OFF_M;
    float* feed = ws + OFF_FEED;
    float* comb = ws + OFF_COMB;
    float* qkv  = ws + OFF_QKV;
    float* mkv  = ws + OFF_MKV;
    float* Zb   = ws + OFF_Z;
    float* iog  = ws + OFF_IOG;
    float* w2g  = ws + OFF_W2G;
    float* w3g  = ws + OFF_W3G;
    float* outp = (float*)d_out;

    k_zero<<<4058, 256, 0, stream>>>(ws, 1038688);
    k_prep_w2g<<<648, 256, 0, stream>>>(conv_w, w2g);
    k_prep_w3g<<<540, 256, 0, stream>>>(o_w, w3g);
    k_feed0<<<216, 256, 0, stream>>>(x, feed);

    for (int t = 0; t < TSTEPS; ++t) {
        k_conv3x3<<<dim3(48, 16), 192, 0, stream>>>(feed, 3, h, HD, w2g, conv_b,
                                                    comb, 4 * HD);
        k_lstm_gates<<<4608, 256, 0, stream>>>(comb, c, h);
        k_qkv<<<dim3(72, 10), 256, 0, stream>>>(h, m, h_w, h_b, m_w, m_b, qkv, mkv);
        k_attn<<<dim3(48, 16), 192, 0, stream>>>(qkv, mkv, z_w, z_b, Zb);
        k_conv3x3<<<dim3(48, 12), 192, 0, stream>>>(Zb, DATT, h, HD, w3g, o_b,
                                                    iog, 3 * HD);
        k_sa_gates<<<4608, 256, 0, stream>>>(iog, m, h);
        k_out_feed<<<72, 256, 0, stream>>>(h, out_w, out_b, x, outp, feed, t);
    }
    k_nino<<<1, 384, 0, stream>>>(outp, outp + (size_t)NB * TSTEPS * NCOUT * SS);
}

// Round 11
// 11702.878 us; speedup vs baseline: 1.0687x; 1.0350x over previous
//
#include <hip/hip_runtime.h>
#include <math.h>

#define HD 64
#define DATT 16
#define NCIN 3
#define NCOUT 2
#define HH 24
#define WW 48
#define SS (HH*WW)          // 1152
#define NB 16
#define TSTEPS 37
#define INPUT_FRAMES 12

#define PR 26
#define PC 52
#define PHW (PR*PC)         // 1352

// ---------------- workspace layout (floats) ----------------
#define OFF_H     0                      // 16*64*1352 = 1384448 (padded)
#define OFF_C     1384448                // 16*64*1152 (unpadded)
#define OFF_M     2564096                // 16*64*1152 (unpadded)
#define OFF_FEED  3743744                // 16*3*1352 (padded)
#define OFF_Z     3808640                // 16*16*1352 (padded)
#define ZERO_END  4154752                // everything above zeroed each launch
#define OFF_COMB  4154752                // 16*256*1152 = 4718592
#define OFF_QKV   4154752                // aliases comb (dead after lstm gates)
#define OFF_MKV   5039488                // qkv + 884736
#define OFF_IOG   8873344                // comb + 4718592
#define OFF_W2G   12412288               // 32*80*9*8 = 184320 (gate conv, padded to 80 ch)
#define OFF_W3G   12596608               // 24*80*9*8 = 138240
// end = 12734848 floats = 50.9 MB

__device__ __forceinline__ float sigmoidf_(float x) {
    return 1.0f / (1.0f + __expf(-x));
}

__global__ void k_zero(float* __restrict__ p, int n4) {
    int i = blockIdx.x * blockDim.x + threadIdx.x;
    if (i < n4) ((float4*)p)[i] = make_float4(0.f, 0.f, 0.f, 0.f);
}

// ---------------- weight reorder: conv_w -> w2g [ocg(32)][c(80)][kt(9)][ocl(8)] ----------------
// zero-padded past c=67 (adds exact +0.0 terms)
__global__ void k_prep_w2g(const float* __restrict__ cw, float* __restrict__ w2g) {
    int idx = blockIdx.x * blockDim.x + threadIdx.x;
    if (idx >= 184320) return;
    int ocl = idx & 7;
    int kt  = (idx >> 3) % 9;
    int c   = (idx / 72) % 80;
    int ocg = idx / 5760;
    w2g[idx] = (c < 67) ? cw[(ocg * 8 + ocl) * 603 + c * 9 + kt] : 0.f;
}

// ---------------- weight reorder: o_w -> w3g [ocg(24)][c(80)][kt(9)][ocl(8)] ----------------
__global__ void k_prep_w3g(const float* __restrict__ ow, float* __restrict__ w3g) {
    int idx = blockIdx.x * blockDim.x + threadIdx.x;
    if (idx >= 138240) return;
    int ocl = idx & 7;
    int kt  = (idx >> 3) % 9;
    int c   = (idx / 72) % 80;
    int ocg = idx / 5760;
    w3g[idx] = ow[(ocg * 8 + ocl) * 720 + c * 9 + kt];
}

// ---------------- initial feed (t=0, always from x) ----------------
__global__ void k_feed0(const float* __restrict__ x, float* __restrict__ feed) {
    int i = blockIdx.x * blockDim.x + threadIdx.x;
    if (i >= NB * 3 * SS) return;
    int s = i % SS;
    int ch = (i / SS) % 3;
    int n = i / (3 * SS);
    int y = s / WW, xx = s % WW;
    float v = x[(((size_t)(n * TSTEPS + 0) * HH + y) * WW + xx) * NCIN + ch];
    feed[((size_t)(n * 3 + ch) * PR + (y + 1)) * PC + (xx + 1)] = v;
}

// ---------------- generic 3x3 conv, pad=1, fp32, padded inputs ----------------
// TWO oc-groups (16 oc) per block (r8); 16-CHANNEL chunks (half the barriers).
// grid: (48, OC/16); block 192 = 24 col-groups (2 px) x 8 rows
__global__ __launch_bounds__(192) void k_conv3x3(
    const float* __restrict__ in1, int C1,
    const float* __restrict__ in2, int C2,
    const float* __restrict__ w, const float* __restrict__ b,
    float* __restrict__ out, int OC)
{
    __shared__ __align__(16) float lds_patch[16 * 520];   // 33.3 KB

    const int bx = blockIdx.x;
    const int n = bx / 3, tile = bx % 3;
    const int ocp = blockIdx.y;                 // oc-pair index
    const int C = C1 + C2;
    const int nchunk = (C + 15) / 16;
    const int tid = threadIdx.x;
    const int y0 = tile * 8;

    const int wgsz = nchunk * 16 * 72;
    const float* wg0 = w + (size_t)(ocp * 2) * wgsz;
    const float* wg1 = wg0 + wgsz;

    const float4* in1_4 = (const float4*)(in1 + (size_t)n * C1 * PHW);
    const float4* in2_4 = (const float4*)(in2 + (size_t)n * C2 * PHW);

    // per-chunk patch: 16 ch x 130 float4 = 2080 f4 ; 192 thr x 11
    float4 pf[11];
    auto load_chunk = [&](int chunk) {
#pragma unroll
        for (int k = 0; k < 11; ++k) {
            int i = tid + 192 * k;
            if (i < 2080) {
                int c_l = i / 130;
                int rem = i - c_l * 130;
                int c = chunk * 16 + c_l;
                float4 v = make_float4(0.f, 0.f, 0.f, 0.f);
                if (c < C) {
                    v = (c < C1) ? in1_4[(c * PR + y0) * 13 + rem]
                                 : in2_4[((c - C1) * PR + y0) * 13 + rem];
                }
                pf[k] = v;
            }
        }
    };

    const int cg = tid % 24;
    const int ty = tid / 24;
    const int x0 = cg * 2;
    const int y_out = y0 + ty;

    float acc[32];
#pragma unroll
    for (int j = 0; j < 32; ++j) acc[j] = 0.f;

    load_chunk(0);
    for (int chunk = 0; chunk < nchunk; ++chunk) {
        __syncthreads();
#pragma unroll
        for (int k = 0; k < 11; ++k) {
            int i = tid + 192 * k;
            if (i < 2080) ((float4*)lds_patch)[i] = pf[k];
        }
        if (chunk + 1 < nchunk) load_chunk(chunk + 1);
        __syncthreads();

        for (int icl = 0; icl < 16; ++icl) {
            const int c = chunk * 16 + icl;
            const float* wb0 = wg0 + c * 72;    // block-uniform (s_load path)
            const float* wb1 = wg1 + c * 72;
            const float* pr = &lds_patch[icl * 520 + ty * PC + x0];
#pragma unroll
            for (int ky = 0; ky < 3; ++ky) {
                const float* r = pr + ky * PC;
                float i0 = r[0], i1 = r[1], i2 = r[2], i3 = r[3];
                const float* wk0 = wb0 + ky * 24;
                const float* wk1 = wb1 + ky * 24;
#pragma unroll
                for (int kx = 0; kx < 3; ++kx) {
                    float va = (kx == 0) ? i0 : ((kx == 1) ? i1 : i2);
                    float vb = (kx == 0) ? i1 : ((kx == 1) ? i2 : i3);
                    const float4 wa0  = *(const float4*)(wk0 + kx * 8);
                    const float4 wb40 = *(const float4*)(wk0 + kx * 8 + 4);
                    const float4 wa1  = *(const float4*)(wk1 + kx * 8);
                    const float4 wb41 = *(const float4*)(wk1 + kx * 8 + 4);
                    acc[0]  += va * wa0.x;  acc[1]  += va * wa0.y;
                    acc[2]  += va * wa0.z;  acc[3]  += va * wa0.w;
                    acc[4]  += va * wb40.x; acc[5]  += va * wb40.y;
                    acc[6]  += va * wb40.z; acc[7]  += va * wb40.w;
                    acc[8]  += vb * wa0.x;  acc[9]  += vb * wa0.y;
                    acc[10] += vb * wa0.z;  acc[11] += vb * wa0.w;
                    acc[12] += vb * wb40.x; acc[13] += vb * wb40.y;
                    acc[14] += vb * wb40.z; acc[15] += vb * wb40.w;
                    acc[16] += va * wa1.x;  acc[17] += va * wa1.y;
                    acc[18] += va * wa1.z;  acc[19] += va * wa1.w;
                    acc[20] += va * wb41.x; acc[21] += va * wb41.y;
                    acc[22] += va * wb41.z; acc[23] += va * wb41.w;
                    acc[24] += vb * wa1.x;  acc[25] += vb * wa1.y;
                    acc[26] += vb * wa1.z;  acc[27] += vb * wa1.w;
                    acc[28] += vb * wb41.x; acc[29] += vb * wb41.y;
                    acc[30] += vb * wb41.z; acc[31] += vb * wb41.w;
                }
            }
        }
    }

#pragma unroll
    for (int j = 0; j < 8; ++j) {
        int oc0 = ocp * 16 + j;
        int oc1 = ocp * 16 + 8 + j;
        float bv0 = b[oc0];
        float bv1 = b[oc1];
        float2 o0 = make_float2(acc[j] + bv0, acc[8 + j] + bv0);
        float2 o1 = make_float2(acc[16 + j] + bv1, acc[24 + j] + bv1);
        *(float2*)&out[((n * OC + oc0) * HH + y_out) * WW + x0] = o0;
        *(float2*)&out[((n * OC + oc1) * HH + y_out) * WW + x0] = o1;
    }
}

// ---------------- ConvLSTM gates (h written padded) ----------------
__global__ void k_lstm_gates(const float* __restrict__ comb, float* __restrict__ c,
                             float* __restrict__ h) {
    int i = blockIdx.x * blockDim.x + threadIdx.x;
    if (i >= NB * HD * SS) return;
    int s = i % SS;
    int ch = (i / SS) % HD;
    int n = i / (HD * SS);
    const float* cb = comb + (size_t)n * 4 * HD * SS;
    float ci = cb[(ch) * SS + s];
    float cf = cb[(ch + HD) * SS + s];
    float co = cb[(ch + 2 * HD) * SS + s];
    float cg = cb[(ch + 3 * HD) * SS + s];
    float ig = sigmoidf_(ci);
    float fg = sigmoidf_(cf);
    float og = sigmoidf_(co);
    float gg = tanhf(cg);
    float cn = fg * c[i] + ig * gg;
    c[i] = cn;
    int y = s / WW, x = s % WW;
    h[((size_t)(n * HD + ch) * PR + (y + 1)) * PC + (x + 1)] = og * tanhf(cn);
}

// ---------------- 1x1 q/k/v + mk/mv projections (10 groups x 8ch) ----------------
__global__ __launch_bounds__(256) void k_qkv(
    const float* __restrict__ h, const float* __restrict__ m,
    const float* __restrict__ hw, const float* __restrict__ hb,
    const float* __restrict__ mw, const float* __restrict__ mb,
    float* __restrict__ qkv, float* __restrict__ mkv) {
    __shared__ float lw[512];
    __shared__ float lb[8];
    const int g = blockIdx.y;
    const int tid = threadIdx.x;
    const float* wsrc = (g < 6) ? (hw + g * 512) : (mw + (g - 6) * 512);
    const float* bsrc = (g < 6) ? (hb + g * 8) : (mb + (g - 6) * 8);
    for (int i = tid; i < 512; i += 256) lw[i] = wsrc[i];
    if (tid < 8) lb[tid] = bsrc[tid];
    __syncthreads();

    int idx = blockIdx.x * 256 + tid;
    int s = idx % SS;
    int n = idx / SS;
    int y = s / WW, x = s % WW;

    float reg[HD];
    if (g < 6) {
        const float* src = h + (size_t)n * HD * PHW + (y + 1) * PC + (x + 1);
#pragma unroll
        for (int ic = 0; ic < HD; ++ic) reg[ic] = src[ic * PHW];
    } else {
        const float* src = m + (size_t)n * HD * SS + s;
#pragma unroll
        for (int ic = 0; ic < HD; ++ic) reg[ic] = src[ic * SS];
    }

    float* dst = (g < 6) ? &qkv[((size_t)n * SS + s) * 48 + g * 8]
                         : &mkv[((size_t)n * SS + s) * 32 + (g - 6) * 8];
#pragma unroll
    for (int j = 0; j < 8; ++j) {
        const float* wr = &lw[j * HD];
        float a = lb[j];
#pragma unroll
        for (int ic = 0; ic < HD; ++ic) a += reg[ic] * wr[ic];
        dst[j] = a;
    }
}

#define LOAD16(dst, srcp) do {                       \
    float4 _a = ((const float4*)(srcp))[0];          \
    float4 _b = ((const float4*)(srcp))[1];          \
    float4 _c = ((const float4*)(srcp))[2];          \
    float4 _d = ((const float4*)(srcp))[3];          \
    dst[0]=_a.x; dst[1]=_a.y; dst[2]=_a.z; dst[3]=_a.w;   \
    dst[4]=_b.x; dst[5]=_b.y; dst[6]=_b.z; dst[7]=_b.w;   \
    dst[8]=_c.x; dst[9]=_c.y; dst[10]=_c.z; dst[11]=_c.w; \
    dst[12]=_d.x; dst[13]=_d.y; dst[14]=_d.z; dst[15]=_d.w; } while(0)

// ---------------- dual spatial attention + z 1x1 (r8-verbatim: best measured) ----------------
// block 256 = 16 row-threads (2 rows each, 32 rows/block) x 16 t-partials; grid (36, 16)
#define TSTRIDE 68
__global__ __launch_bounds__(256) void k_attn(
    const float* __restrict__ qkv, const float* __restrict__ mkv,
    const float* __restrict__ zw, const float* __restrict__ zb,
    float* __restrict__ Z)
{
    __shared__ __align__(16) float smem[144 * TSTRIDE];  // 38.3 KB
    const int n = blockIdx.y;
    const int tid = threadIdx.x;
    const int rowthr = tid >> 4;    // 0..15
    const int part = tid & 15;      // 0..15 (== lane & 15)
    const int s0 = blockIdx.x * 32 + rowthr * 2;

    float q0[16], q1[16];
    LOAD16(q0, &qkv[((size_t)n * SS + s0) * 48]);
    LOAD16(q1, &qkv[((size_t)n * SS + s0 + 1) * 48]);

    float lh0 = 0.f, lh1 = 0.f, lm0 = 0.f, lm1 = 0.f;
    float oh0[16], oh1[16], om0[16], om1[16];
#pragma unroll
    for (int j = 0; j < 16; ++j) { oh0[j] = 0.f; oh1[j] = 0.f; om0[j] = 0.f; om1[j] = 0.f; }

    const float4* qkv4 = (const float4*)qkv + (size_t)n * SS * 12;
    const float4* mkv4 = (const float4*)mkv + (size_t)n * SS * 8;

    for (int tile = 0; tile < 8; ++tile) {
        __syncthreads();
        // stage 144 t: [t][hk16|hv16|mk16|mv16] at stride 68 floats
#pragma unroll
        for (int k = 0; k < 9; ++k) {
            int j = tid + 256 * k;
            int t_loc = j >> 4, f = j & 15;
            int t = tile * 144 + t_loc;
            float4 v;
            if (f < 8) v = qkv4[t * 12 + 4 + f];
            else       v = mkv4[t * 8 + (f - 8)];
            *(float4*)&smem[t_loc * TSTRIDE + f * 4] = v;
        }
        __syncthreads();

        const int t0 = part * 9;
        for (int tl = t0; tl < t0 + 9; ++tl) {
            const float* kvb = &smem[tl * TSTRIDE];
            float kk[16], vv[16];
            LOAD16(kk, kvb);
            float d0 = 0.f, d1 = 0.f;
#pragma unroll
            for (int j = 0; j < 16; ++j) { d0 += q0[j] * kk[j]; d1 += q1[j] * kk[j]; }
            float e0 = __expf(d0 * 0.25f), e1 = __expf(d1 * 0.25f);
            lh0 += e0; lh1 += e1;
            LOAD16(vv, kvb + 16);
#pragma unroll
            for (int j = 0; j < 16; ++j) { oh0[j] += e0 * vv[j]; oh1[j] += e1 * vv[j]; }
            LOAD16(kk, kvb + 32);
            float f0 = 0.f, f1 = 0.f;
#pragma unroll
            for (int j = 0; j < 16; ++j) { f0 += q0[j] * kk[j]; f1 += q1[j] * kk[j]; }
            float g0 = __expf(f0 * 0.25f), g1 = __expf(f1 * 0.25f);
            lm0 += g0; lm1 += g1;
            LOAD16(vv, kvb + 48);
#pragma unroll
            for (int j = 0; j < 16; ++j) { om0[j] += g0 * vv[j]; om1[j] += g1 * vv[j]; }
        }
    }

    // butterfly all-reduce across the 16 partials (lane bits 0..3)
#pragma unroll
    for (int mask = 1; mask <= 8; mask <<= 1) {
        lh0 += __shfl_xor(lh0, mask, 16);
        lh1 += __shfl_xor(lh1, mask, 16);
        lm0 += __shfl_xor(lm0, mask, 16);
        lm1 += __shfl_xor(lm1, mask, 16);
#pragma unroll
        for (int j = 0; j < 16; ++j) {
            oh0[j] += __shfl_xor(oh0[j], mask, 16);
            oh1[j] += __shfl_xor(oh1[j], mask, 16);
            om0[j] += __shfl_xor(om0[j], mask, 16);
            om1[j] += __shfl_xor(om1[j], mask, 16);
        }
    }

    const int zc = part;
    const float* zr = &zw[zc * 32];
    float zrh[16], zrm[16];
    LOAD16(zrh, zr);
    LOAD16(zrm, zr + 16);
    float zbv = zb[zc];
    float ilh0 = 1.f / lh0, ilh1 = 1.f / lh1;
    float ilm0 = 1.f / lm0, ilm1 = 1.f / lm1;
    float a0 = zbv, a1 = zbv;
#pragma unroll
    for (int j = 0; j < 16; ++j) {
        a0 += zrh[j] * (oh0[j] * ilh0) + zrm[j] * (om0[j] * ilm0);
        a1 += zrh[j] * (oh1[j] * ilh1) + zrm[j] * (om1[j] * ilm1);
    }
    {
        int y0_ = s0 / WW, x0_ = s0 % WW;
        Z[((size_t)(n * DATT + zc) * PR + y0_ + 1) * PC + x0_ + 1] = a0;
        int y1_ = (s0 + 1) / WW, x1_ = (s0 + 1) % WW;
        Z[((size_t)(n * DATT + zc) * PR + y1_ + 1) * PC + x1_ + 1] = a1;
    }
}

// ---------------- SA memory gates (h written padded) ----------------
__global__ void k_sa_gates(const float* __restrict__ iog, float* __restrict__ m,
                           float* __restrict__ h) {
    int i = blockIdx.x * blockDim.x + threadIdx.x;
    if (i >= NB * HD * SS) return;
    int s = i % SS;
    int ch = (i / SS) % HD;
    int n = i / (HD * SS);
    const float* ib = iog + (size_t)n * 3 * HD * SS;
    float si = ib[ch * SS + s];
    float sg = ib[(HD + ch) * SS + s];
    float so = ib[(2 * HD + ch) * SS + s];
    si = sigmoidf_(si);
    sg = tanhf(sg);
    float mn = si * sg + (1.f - si) * m[i];
    m[i] = mn;
    int y = s / WW, x = s % WW;
    h[((size_t)(n * HD + ch) * PR + (y + 1)) * PC + (x + 1)] = sigmoidf_(so) * mn;
}

// ---------------- out 1x1 (64->2) + next-step feed, fused ----------------
__global__ void k_out_feed(const float* __restrict__ h, const float* __restrict__ ow,
                           const float* __restrict__ ob, const float* __restrict__ x,
                           float* __restrict__ outbuf, float* __restrict__ feed, int t) {
    int idx = blockIdx.x * 256 + threadIdx.x;
    if (idx >= NB * SS) return;
    int s = idx % SS;
    int n = idx / SS;
    int y = s / WW, xx = s % WW;
    const float* src = h + (size_t)n * HD * PHW + (y + 1) * PC + (xx + 1);
    float o0 = ob[0], o1 = ob[1];
#pragma unroll
    for (int ic = 0; ic < HD; ++ic) {
        float r = src[ic * PHW];
        o0 += r * ow[ic];
        o1 += r * ow[HD + ic];
    }
    outbuf[(((size_t)n * TSTEPS + t) * NCOUT + 0) * SS + s] = o0;
    outbuf[(((size_t)n * TSTEPS + t) * NCOUT + 1) * SS + s] = o1;

    if (t + 1 < TSTEPS) {
        int t1 = t + 1;
        const float* xp = &x[(((size_t)(n * TSTEPS + t1) * HH + y) * WW + xx) * NCIN];
        float f0, f1, f2 = xp[2];
        if (t1 < INPUT_FRAMES) { f0 = xp[0]; f1 = xp[1]; }
        else { f0 = o0; f1 = o1; }
        size_t fb = ((size_t)(n * 3 + 0) * PR + y + 1) * PC + xx + 1;
        feed[fb] = f0;
        feed[fb + PHW] = f1;
        feed[fb + 2 * (size_t)PHW] = f2;
    }
}

// ---------------- nino prediction ----------------
__global__ void k_nino(const float* __restrict__ outbuf, float* __restrict__ pred) {
    int tidx = threadIdx.x;
    if (tidx >= 16 * 24) return;
    int j = tidx % 24;
    int n = tidx / 24;
    float acc = 0.f;
    for (int f = j; f < j + 3; ++f) {
        int t = 11 + f;
        const float* p = &outbuf[(((size_t)n * TSTEPS + t) * NCOUT + 0) * SS];
        float sloc = 0.f;
        for (int y = 10; y <= 12; ++y)
            for (int x = 19; x <= 29; ++x)
                sloc += p[y * WW + x];
        acc += sloc * (1.f / 33.f);
    }
    pred[n * 24 + j] = acc * (1.f / 3.f);
}

extern "C" void kernel_launch(void* const* d_in, const int* in_sizes, int n_in,
                              void* d_out, int out_size, void* d_ws, size_t ws_size,
                              hipStream_t stream) {
    const float* x      = (const float*)d_in[0];
    const float* conv_w = (const float*)d_in[1];
    const float* conv_b = (const float*)d_in[2];
    const float* h_w    = (const float*)d_in[3];
    const float* h_b    = (const float*)d_in[4];
    const float* m_w    = (const float*)d_in[5];
    const float* m_b    = (const float*)d_in[6];
    const float* z_w    = (const float*)d_in[7];
    const float* z_b    = (const float*)d_in[8];
    const float* o_w    = (const float*)d_in[9];
    const float* o_b    = (const float*)d_in[10];
    const float* out_w  = (const float*)d_in[11];
    const float* out_b  = (const float*)d_in[12];

    float* ws   = (float*)d_ws;
    float* h    = ws + OFF_H;
    float* c    = ws + OFF_C;
    float* m    = ws + OFF_M;
    float* feed = ws + OFF_FEED;
    float* comb = ws + OFF_COMB;
    float* qkv  = ws + OFF_QKV;
    float* mkv  = ws + OFF_MKV;
    float* Zb   = ws + OFF_Z;
    float* iog  = ws + OFF_IOG;
    float* w2g  = ws + OFF_W2G;
    float* w3g  = ws + OFF_W3G;
    float* outp = (float*)d_out;

    k_zero<<<4058, 256, 0, stream>>>(ws, 1038688);
    k_prep_w2g<<<720, 256, 0, stream>>>(conv_w, w2g);
    k_prep_w3g<<<540, 256, 0, stream>>>(o_w, w3g);
    k_feed0<<<216, 256, 0, stream>>>(x, feed);

    for (int t = 0; t < TSTEPS; ++t) {
        k_conv3x3<<<dim3(48, 16), 192, 0, stream>>>(feed, 3, h, HD, w2g, conv_b,
                                                    comb, 4 * HD);
        k_lstm_gates<<<4608, 256, 0, stream>>>(comb, c, h);
        k_qkv<<<dim3(72, 10), 256, 0, stream>>>(h, m, h_w, h_b, m_w, m_b, qkv, mkv);
        k_attn<<<dim3(36, 16), 256, 0, stream>>>(qkv, mkv, z_w, z_b, Zb);
        k_conv3x3<<<dim3(48, 12), 192, 0, stream>>>(Zb, DATT, h, HD, w3g, o_b,
                                                    iog, 3 * HD);
        k_sa_gates<<<4608, 256, 0, stream>>>(iog, m, h);
        k_out_feed<<<72, 256, 0, stream>>>(h, out_w, out_b, x, outp, feed, t);
    }
    k_nino<<<1, 384, 0, stream>>>(outp, outp + (size_t)NB * TSTEPS * NCOUT * SS);
}

// Round 12
// 11242.934 us; speedup vs baseline: 1.1124x; 1.0409x over previous
//
#include <hip/hip_runtime.h>
#include <math.h>

#define HD 64
#define DATT 16
#define NCIN 3
#define NCOUT 2
#define HH 24
#define WW 48
#define SS (HH*WW)          // 1152
#define NB 16
#define TSTEPS 37
#define INPUT_FRAMES 12

#define PR 26
#define PC 52
#define PHW (PR*PC)         // 1352

// ---------------- workspace layout (floats) ----------------
#define OFF_H     0                      // hA: post-LSTM h, 16*64*1352 = 1384448 (padded)
#define OFF_C     1384448                // 16*64*1152 (unpadded)
#define OFF_M     2564096                // 16*64*1152 (unpadded)
#define OFF_FEED  3743744                // 16*3*1352 (padded)
#define OFF_Z     3808640                // 16*16*1352 (padded)
#define ZERO_END  4154752                // zeroed each launch (1038688 f4)
#define OFF_QKV   4154752                // 16*1152*48 = 884736
#define OFF_MKV   5039488                // 16*1152*32 = 589824
#define OFF_HB    5629312                // hB: carry h (padded) = 1384448, zero-init separately
#define OFF_IOG   8873344                // 16*192*1152 = 3538944
#define OFF_W2G   12412288               // 32*80*9*8 = 184320 (gate conv, oc-permuted)
#define OFF_B2P   12596608               // 256 (permuted gate-conv bias)
#define OFF_W3G   12596864               // 24*80*9*8 = 138240
// end = 12735104 floats = 50.9 MB

__device__ __forceinline__ float sigmoidf_(float x) {
    return 1.0f / (1.0f + __expf(-x));
}

__global__ void k_zero(float* __restrict__ p, int n4) {
    int i = blockIdx.x * blockDim.x + threadIdx.x;
    if (i < n4) ((float4*)p)[i] = make_float4(0.f, 0.f, 0.f, 0.f);
}

// ---- weight reorder: conv_w -> w2g [ocg(32)][c(80)][kt(9)][ocl(8)], oc PERMUTED ----
// permuted channel oc' = ocg*8+ocl encodes ch = oc'>>2, gate = oc'&3;
// original oc = gate*64 + ch. Zero-padded past c=67. Also permuted bias b2p.
__global__ void k_prep_w2g(const float* __restrict__ cw, const float* __restrict__ cb,
                           float* __restrict__ w2g, float* __restrict__ b2p) {
    int idx = blockIdx.x * blockDim.x + threadIdx.x;
    if (idx < 184320) {
        int ocl = idx & 7;
        int kt  = (idx >> 3) % 9;
        int c   = (idx / 72) % 80;
        int ocg = idx / 5760;
        int ocp_ = ocg * 8 + ocl;                       // permuted index
        int oc_orig = ((ocp_ & 3) << 6) + (ocp_ >> 2);  // gate*64 + ch
        w2g[idx] = (c < 67) ? cw[oc_orig * 603 + c * 9 + kt] : 0.f;
    } else if (idx < 184576) {
        int ocp_ = idx - 184320;
        b2p[ocp_] = cb[((ocp_ & 3) << 6) + (ocp_ >> 2)];
    }
}

// ---- weight reorder: o_w -> w3g [ocg(24)][c(80)][kt(9)][ocl(8)] (r11-verbatim) ----
__global__ void k_prep_w3g(const float* __restrict__ ow, float* __restrict__ w3g) {
    int idx = blockIdx.x * blockDim.x + threadIdx.x;
    if (idx >= 138240) return;
    int ocl = idx & 7;
    int kt  = (idx >> 3) % 9;
    int c   = (idx / 72) % 80;
    int ocg = idx / 5760;
    w3g[idx] = ow[(ocg * 8 + ocl) * 720 + c * 9 + kt];
}

// ---------------- initial feed (t=0, always from x) ----------------
__global__ void k_feed0(const float* __restrict__ x, float* __restrict__ feed) {
    int i = blockIdx.x * blockDim.x + threadIdx.x;
    if (i >= NB * 3 * SS) return;
    int s = i % SS;
    int ch = (i / SS) % 3;
    int n = i / (3 * SS);
    int y = s / WW, xx = s % WW;
    float v = x[(((size_t)(n * TSTEPS + 0) * HH + y) * WW + xx) * NCIN + ch];
    feed[((size_t)(n * 3 + ch) * PR + (y + 1)) * PC + (xx + 1)] = v;
}

// ---------------- gate conv 3x3 + FUSED LSTM gates ----------------
// Body identical to the passing r11 conv (16-ch chunks, two 8-oc groups/block);
// oc dimension is permuted (ch*4+gate) so each block owns 4 ch x 4 gates.
// grid (48, 16), block 192. Reads hin (carry, padded), writes c + hout (post-LSTM).
__global__ __launch_bounds__(192) void k_conv_lstm(
    const float* __restrict__ feed, const float* __restrict__ hin,
    const float* __restrict__ w, const float* __restrict__ b,
    float* __restrict__ c, float* __restrict__ hout)
{
    __shared__ __align__(16) float lds_patch[16 * 520];   // 33.3 KB

    const int bx = blockIdx.x;
    const int n = bx / 3, tile = bx % 3;
    const int ocp = blockIdx.y;
    const int tid = threadIdx.x;
    const int y0 = tile * 8;

    const int wgsz = 5 * 16 * 72;                         // nchunk=5 (C=67->80)
    const float* wg0 = w + (size_t)(ocp * 2) * wgsz;
    const float* wg1 = wg0 + wgsz;

    const float4* in1_4 = (const float4*)(feed + (size_t)n * 3 * PHW);
    const float4* in2_4 = (const float4*)(hin + (size_t)n * HD * PHW);

    float4 pf[11];
    auto load_chunk = [&](int chunk) {
#pragma unroll
        for (int k = 0; k < 11; ++k) {
            int i = tid + 192 * k;
            if (i < 2080) {
                int c_l = i / 130;
                int rem = i - c_l * 130;
                int cc = chunk * 16 + c_l;
                float4 v = make_float4(0.f, 0.f, 0.f, 0.f);
                if (cc < 67) {
                    v = (cc < 3) ? in1_4[(cc * PR + y0) * 13 + rem]
                                 : in2_4[((cc - 3) * PR + y0) * 13 + rem];
                }
                pf[k] = v;
            }
        }
    };

    const int cg = tid % 24;
    const int ty = tid / 24;
    const int x0 = cg * 2;
    const int y_out = y0 + ty;

    float acc[32];
#pragma unroll
    for (int j = 0; j < 32; ++j) acc[j] = 0.f;

    load_chunk(0);
    for (int chunk = 0; chunk < 5; ++chunk) {
        __syncthreads();
#pragma unroll
        for (int k = 0; k < 11; ++k) {
            int i = tid + 192 * k;
            if (i < 2080) ((float4*)lds_patch)[i] = pf[k];
        }
        if (chunk + 1 < 5) load_chunk(chunk + 1);
        __syncthreads();

        for (int icl = 0; icl < 16; ++icl) {
            const int cc = chunk * 16 + icl;
            const float* wb0 = wg0 + cc * 72;
            const float* wb1 = wg1 + cc * 72;
            const float* pr = &lds_patch[icl * 520 + ty * PC + x0];
#pragma unroll
            for (int ky = 0; ky < 3; ++ky) {
                const float* r = pr + ky * PC;
                float i0 = r[0], i1 = r[1], i2 = r[2], i3 = r[3];
                const float* wk0 = wb0 + ky * 24;
                const float* wk1 = wb1 + ky * 24;
#pragma unroll
                for (int kx = 0; kx < 3; ++kx) {
                    float va = (kx == 0) ? i0 : ((kx == 1) ? i1 : i2);
                    float vb = (kx == 0) ? i1 : ((kx == 1) ? i2 : i3);
                    const float4 wa0  = *(const float4*)(wk0 + kx * 8);
                    const float4 wb40 = *(const float4*)(wk0 + kx * 8 + 4);
                    const float4 wa1  = *(const float4*)(wk1 + kx * 8);
                    const float4 wb41 = *(const float4*)(wk1 + kx * 8 + 4);
                    acc[0]  += va * wa0.x;  acc[1]  += va * wa0.y;
                    acc[2]  += va * wa0.z;  acc[3]  += va * wa0.w;
                    acc[4]  += va * wb40.x; acc[5]  += va * wb40.y;
                    acc[6]  += va * wb40.z; acc[7]  += va * wb40.w;
                    acc[8]  += vb * wa0.x;  acc[9]  += vb * wa0.y;
                    acc[10] += vb * wa0.z;  acc[11] += vb * wa0.w;
                    acc[12] += vb * wb40.x; acc[13] += vb * wb40.y;
                    acc[14] += vb * wb40.z; acc[15] += vb * wb40.w;
                    acc[16] += va * wa1.x;  acc[17] += va * wa1.y;
                    acc[18] += va * wa1.z;  acc[19] += va * wa1.w;
                    acc[20] += va * wb41.x; acc[21] += va * wb41.y;
                    acc[22] += va * wb41.z; acc[23] += va * wb41.w;
                    acc[24] += vb * wa1.x;  acc[25] += vb * wa1.y;
                    acc[26] += vb * wa1.z;  acc[27] += vb * wa1.w;
                    acc[28] += vb * wb41.x; acc[29] += vb * wb41.y;
                    acc[30] += vb * wb41.z; acc[31] += vb * wb41.w;
                }
            }
        }
    }

    // fused LSTM epilogue. acc map (r11 store order): oc_local ol in [0,16):
    //   ol<8 : px0->acc[ol],    px1->acc[8+ol]
    //   ol>=8: px0->acc[8+ol],  px1->acc[16+ol]
    // permuted oc' = ocp*16+ol = ch*4+gate -> ol = chl*4+gate, ch = ocp*4+chl
    const float* bb = b + ocp * 16;
#pragma unroll
    for (int chl = 0; chl < 4; ++chl) {
        const int ch = ocp * 4 + chl;
#pragma unroll
        for (int px = 0; px < 2; ++px) {
            const int base = chl * 4 + 8 * px + ((chl >= 2) ? 8 : 0);
            float iv = sigmoidf_(acc[base]     + bb[chl * 4 + 0]);
            float fv = sigmoidf_(acc[base + 1] + bb[chl * 4 + 1]);
            float ov = sigmoidf_(acc[base + 2] + bb[chl * 4 + 2]);
            float gv = tanhf    (acc[base + 3] + bb[chl * 4 + 3]);
            size_t ci_ = ((size_t)(n * HD + ch) * HH + y_out) * WW + x0 + px;
            float cn = fv * c[ci_] + iv * gv;
            c[ci_] = cn;
            hout[((size_t)(n * HD + ch) * PR + y_out + 1) * PC + x0 + px + 1] = ov * tanhf(cn);
        }
    }
}

// ---------------- generic 3x3 conv (r11-verbatim; used for out conv) ----------------
__global__ __launch_bounds__(192) void k_conv3x3(
    const float* __restrict__ in1, int C1,
    const float* __restrict__ in2, int C2,
    const float* __restrict__ w, const float* __restrict__ b,
    float* __restrict__ out, int OC)
{
    __shared__ __align__(16) float lds_patch[16 * 520];

    const int bx = blockIdx.x;
    const int n = bx / 3, tile = bx % 3;
    const int ocp = blockIdx.y;
    const int C = C1 + C2;
    const int nchunk = (C + 15) / 16;
    const int tid = threadIdx.x;
    const int y0 = tile * 8;

    const int wgsz = nchunk * 16 * 72;
    const float* wg0 = w + (size_t)(ocp * 2) * wgsz;
    const float* wg1 = wg0 + wgsz;

    const float4* in1_4 = (const float4*)(in1 + (size_t)n * C1 * PHW);
    const float4* in2_4 = (const float4*)(in2 + (size_t)n * C2 * PHW);

    float4 pf[11];
    auto load_chunk = [&](int chunk) {
#pragma unroll
        for (int k = 0; k < 11; ++k) {
            int i = tid + 192 * k;
            if (i < 2080) {
                int c_l = i / 130;
                int rem = i - c_l * 130;
                int c = chunk * 16 + c_l;
                float4 v = make_float4(0.f, 0.f, 0.f, 0.f);
                if (c < C) {
                    v = (c < C1) ? in1_4[(c * PR + y0) * 13 + rem]
                                 : in2_4[((c - C1) * PR + y0) * 13 + rem];
                }
                pf[k] = v;
            }
        }
    };

    const int cg = tid % 24;
    const int ty = tid / 24;
    const int x0 = cg * 2;
    const int y_out = y0 + ty;

    float acc[32];
#pragma unroll
    for (int j = 0; j < 32; ++j) acc[j] = 0.f;

    load_chunk(0);
    for (int chunk = 0; chunk < nchunk; ++chunk) {
        __syncthreads();
#pragma unroll
        for (int k = 0; k < 11; ++k) {
            int i = tid + 192 * k;
            if (i < 2080) ((float4*)lds_patch)[i] = pf[k];
        }
        if (chunk + 1 < nchunk) load_chunk(chunk + 1);
        __syncthreads();

        for (int icl = 0; icl < 16; ++icl) {
            const int c = chunk * 16 + icl;
            const float* wb0 = wg0 + c * 72;
            const float* wb1 = wg1 + c * 72;
            const float* pr = &lds_patch[icl * 520 + ty * PC + x0];
#pragma unroll
            for (int ky = 0; ky < 3; ++ky) {
                const float* r = pr + ky * PC;
                float i0 = r[0], i1 = r[1], i2 = r[2], i3 = r[3];
                const float* wk0 = wb0 + ky * 24;
                const float* wk1 = wb1 + ky * 24;
#pragma unroll
                for (int kx = 0; kx < 3; ++kx) {
                    float va = (kx == 0) ? i0 : ((kx == 1) ? i1 : i2);
                    float vb = (kx == 0) ? i1 : ((kx == 1) ? i2 : i3);
                    const float4 wa0  = *(const float4*)(wk0 + kx * 8);
                    const float4 wb40 = *(const float4*)(wk0 + kx * 8 + 4);
                    const float4 wa1  = *(const float4*)(wk1 + kx * 8);
                    const float4 wb41 = *(const float4*)(wk1 + kx * 8 + 4);
                    acc[0]  += va * wa0.x;  acc[1]  += va * wa0.y;
                    acc[2]  += va * wa0.z;  acc[3]  += va * wa0.w;
                    acc[4]  += va * wb40.x; acc[5]  += va * wb40.y;
                    acc[6]  += va * wb40.z; acc[7]  += va * wb40.w;
                    acc[8]  += vb * wa0.x;  acc[9]  += vb * wa0.y;
                    acc[10] += vb * wa0.z;  acc[11] += vb * wa0.w;
                    acc[12] += vb * wb40.x; acc[13] += vb * wb40.y;
                    acc[14] += vb * wb40.z; acc[15] += vb * wb40.w;
                    acc[16] += va * wa1.x;  acc[17] += va * wa1.y;
                    acc[18] += va * wa1.z;  acc[19] += va * wa1.w;
                    acc[20] += va * wb41.x; acc[21] += va * wb41.y;
                    acc[22] += va * wb41.z; acc[23] += va * wb41.w;
                    acc[24] += vb * wa1.x;  acc[25] += vb * wa1.y;
                    acc[26] += vb * wa1.z;  acc[27] += vb * wa1.w;
                    acc[28] += vb * wb41.x; acc[29] += vb * wb41.y;
                    acc[30] += vb * wb41.z; acc[31] += vb * wb41.w;
                }
            }
        }
    }

#pragma unroll
    for (int j = 0; j < 8; ++j) {
        int oc0 = ocp * 16 + j;
        int oc1 = ocp * 16 + 8 + j;
        float bv0 = b[oc0];
        float bv1 = b[oc1];
        float2 o0 = make_float2(acc[j] + bv0, acc[8 + j] + bv0);
        float2 o1 = make_float2(acc[16 + j] + bv1, acc[24 + j] + bv1);
        *(float2*)&out[((n * OC + oc0) * HH + y_out) * WW + x0] = o0;
        *(float2*)&out[((n * OC + oc1) * HH + y_out) * WW + x0] = o1;
    }
}

// ---------------- 1x1 q/k/v + mk/mv projections (10 groups x 8ch) ----------------
__global__ __launch_bounds__(256) void k_qkv(
    const float* __restrict__ h, const float* __restrict__ m,
    const float* __restrict__ hw, const float* __restrict__ hb,
    const float* __restrict__ mw, const float* __restrict__ mb,
    float* __restrict__ qkv, float* __restrict__ mkv) {
    __shared__ float lw[512];
    __shared__ float lb[8];
    const int g = blockIdx.y;
    const int tid = threadIdx.x;
    const float* wsrc = (g < 6) ? (hw + g * 512) : (mw + (g - 6) * 512);
    const float* bsrc = (g < 6) ? (hb + g * 8) : (mb + (g - 6) * 8);
    for (int i = tid; i < 512; i += 256) lw[i] = wsrc[i];
    if (tid < 8) lb[tid] = bsrc[tid];
    __syncthreads();

    int idx = blockIdx.x * 256 + tid;
    int s = idx % SS;
    int n = idx / SS;
    int y = s / WW, x = s % WW;

    float reg[HD];
    if (g < 6) {
        const float* src = h + (size_t)n * HD * PHW + (y + 1) * PC + (x + 1);
#pragma unroll
        for (int ic = 0; ic < HD; ++ic) reg[ic] = src[ic * PHW];
    } else {
        const float* src = m + (size_t)n * HD * SS + s;
#pragma unroll
        for (int ic = 0; ic < HD; ++ic) reg[ic] = src[ic * SS];
    }

    float* dst = (g < 6) ? &qkv[((size_t)n * SS + s) * 48 + g * 8]
                         : &mkv[((size_t)n * SS + s) * 32 + (g - 6) * 8];
#pragma unroll
    for (int j = 0; j < 8; ++j) {
        const float* wr = &lw[j * HD];
        float a = lb[j];
#pragma unroll
        for (int ic = 0; ic < HD; ++ic) a += reg[ic] * wr[ic];
        dst[j] = a;
    }
}

#define LOAD16(dst, srcp) do {                       \
    float4 _a = ((const float4*)(srcp))[0];          \
    float4 _b = ((const float4*)(srcp))[1];          \
    float4 _c = ((const float4*)(srcp))[2];          \
    float4 _d = ((const float4*)(srcp))[3];          \
    dst[0]=_a.x; dst[1]=_a.y; dst[2]=_a.z; dst[3]=_a.w;   \
    dst[4]=_b.x; dst[5]=_b.y; dst[6]=_b.z; dst[7]=_b.w;   \
    dst[8]=_c.x; dst[9]=_c.y; dst[10]=_c.z; dst[11]=_c.w; \
    dst[12]=_d.x; dst[13]=_d.y; dst[14]=_d.z; dst[15]=_d.w; } while(0)

// ---------------- dual spatial attention + z 1x1 (r8-verbatim: best measured) ----------------
#define TSTRIDE 68
__global__ __launch_bounds__(256) void k_attn(
    const float* __restrict__ qkv, const float* __restrict__ mkv,
    const float* __restrict__ zw, const float* __restrict__ zb,
    float* __restrict__ Z)
{
    __shared__ __align__(16) float smem[144 * TSTRIDE];
    const int n = blockIdx.y;
    const int tid = threadIdx.x;
    const int rowthr = tid >> 4;
    const int part = tid & 15;
    const int s0 = blockIdx.x * 32 + rowthr * 2;

    float q0[16], q1[16];
    LOAD16(q0, &qkv[((size_t)n * SS + s0) * 48]);
    LOAD16(q1, &qkv[((size_t)n * SS + s0 + 1) * 48]);

    float lh0 = 0.f, lh1 = 0.f, lm0 = 0.f, lm1 = 0.f;
    float oh0[16], oh1[16], om0[16], om1[16];
#pragma unroll
    for (int j = 0; j < 16; ++j) { oh0[j] = 0.f; oh1[j] = 0.f; om0[j] = 0.f; om1[j] = 0.f; }

    const float4* qkv4 = (const float4*)qkv + (size_t)n * SS * 12;
    const float4* mkv4 = (const float4*)mkv + (size_t)n * SS * 8;

    for (int tile = 0; tile < 8; ++tile) {
        __syncthreads();
#pragma unroll
        for (int k = 0; k < 9; ++k) {
            int j = tid + 256 * k;
            int t_loc = j >> 4, f = j & 15;
            int t = tile * 144 + t_loc;
            float4 v;
            if (f < 8) v = qkv4[t * 12 + 4 + f];
            else       v = mkv4[t * 8 + (f - 8)];
            *(float4*)&smem[t_loc * TSTRIDE + f * 4] = v;
        }
        __syncthreads();

        const int t0 = part * 9;
        for (int tl = t0; tl < t0 + 9; ++tl) {
            const float* kvb = &smem[tl * TSTRIDE];
            float kk[16], vv[16];
            LOAD16(kk, kvb);
            float d0 = 0.f, d1 = 0.f;
#pragma unroll
            for (int j = 0; j < 16; ++j) { d0 += q0[j] * kk[j]; d1 += q1[j] * kk[j]; }
            float e0 = __expf(d0 * 0.25f), e1 = __expf(d1 * 0.25f);
            lh0 += e0; lh1 += e1;
            LOAD16(vv, kvb + 16);
#pragma unroll
            for (int j = 0; j < 16; ++j) { oh0[j] += e0 * vv[j]; oh1[j] += e1 * vv[j]; }
            LOAD16(kk, kvb + 32);
            float f0 = 0.f, f1 = 0.f;
#pragma unroll
            for (int j = 0; j < 16; ++j) { f0 += q0[j] * kk[j]; f1 += q1[j] * kk[j]; }
            float g0 = __expf(f0 * 0.25f), g1 = __expf(f1 * 0.25f);
            lm0 += g0; lm1 += g1;
            LOAD16(vv, kvb + 48);
#pragma unroll
            for (int j = 0; j < 16; ++j) { om0[j] += g0 * vv[j]; om1[j] += g1 * vv[j]; }
        }
    }

#pragma unroll
    for (int mask = 1; mask <= 8; mask <<= 1) {
        lh0 += __shfl_xor(lh0, mask, 16);
        lh1 += __shfl_xor(lh1, mask, 16);
        lm0 += __shfl_xor(lm0, mask, 16);
        lm1 += __shfl_xor(lm1, mask, 16);
#pragma unroll
        for (int j = 0; j < 16; ++j) {
            oh0[j] += __shfl_xor(oh0[j], mask, 16);
            oh1[j] += __shfl_xor(oh1[j], mask, 16);
            om0[j] += __shfl_xor(om0[j], mask, 16);
            om1[j] += __shfl_xor(om1[j], mask, 16);
        }
    }

    const int zc = part;
    const float* zr = &zw[zc * 32];
    float zrh[16], zrm[16];
    LOAD16(zrh, zr);
    LOAD16(zrm, zr + 16);
    float zbv = zb[zc];
    float ilh0 = 1.f / lh0, ilh1 = 1.f / lh1;
    float ilm0 = 1.f / lm0, ilm1 = 1.f / lm1;
    float a0 = zbv, a1 = zbv;
#pragma unroll
    for (int j = 0; j < 16; ++j) {
        a0 += zrh[j] * (oh0[j] * ilh0) + zrm[j] * (om0[j] * ilm0);
        a1 += zrh[j] * (oh1[j] * ilh1) + zrm[j] * (om1[j] * ilm1);
    }
    {
        int y0_ = s0 / WW, x0_ = s0 % WW;
        Z[((size_t)(n * DATT + zc) * PR + y0_ + 1) * PC + x0_ + 1] = a0;
        int y1_ = (s0 + 1) / WW, x1_ = (s0 + 1) % WW;
        Z[((size_t)(n * DATT + zc) * PR + y1_ + 1) * PC + x1_ + 1] = a1;
    }
}

// ---------------- SA memory gates (writes carry h = hB, padded) ----------------
__global__ void k_sa_gates(const float* __restrict__ iog, float* __restrict__ m,
                           float* __restrict__ h) {
    int i = blockIdx.x * blockDim.x + threadIdx.x;
    if (i >= NB * HD * SS) return;
    int s = i % SS;
    int ch = (i / SS) % HD;
    int n = i / (HD * SS);
    const float* ib = iog + (size_t)n * 3 * HD * SS;
    float si = ib[ch * SS + s];
    float sg = ib[(HD + ch) * SS + s];
    float so = ib[(2 * HD + ch) * SS + s];
    si = sigmoidf_(si);
    sg = tanhf(sg);
    float mn = si * sg + (1.f - si) * m[i];
    m[i] = mn;
    int y = s / WW, x = s % WW;
    h[((size_t)(n * HD + ch) * PR + (y + 1)) * PC + (x + 1)] = sigmoidf_(so) * mn;
}

// ---------------- out 1x1 (64->2) + next-step feed, fused (reads hB) ----------------
__global__ void k_out_feed(const float* __restrict__ h, const float* __restrict__ ow,
                           const float* __restrict__ ob, const float* __restrict__ x,
                           float* __restrict__ outbuf, float* __restrict__ feed, int t) {
    int idx = blockIdx.x * 256 + threadIdx.x;
    if (idx >= NB * SS) return;
    int s = idx % SS;
    int n = idx / SS;
    int y = s / WW, xx = s % WW;
    const float* src = h + (size_t)n * HD * PHW + (y + 1) * PC + (xx + 1);
    float o0 = ob[0], o1 = ob[1];
#pragma unroll
    for (int ic = 0; ic < HD; ++ic) {
        float r = src[ic * PHW];
        o0 += r * ow[ic];
        o1 += r * ow[HD + ic];
    }
    outbuf[(((size_t)n * TSTEPS + t) * NCOUT + 0) * SS + s] = o0;
    outbuf[(((size_t)n * TSTEPS + t) * NCOUT + 1) * SS + s] = o1;

    if (t + 1 < TSTEPS) {
        int t1 = t + 1;
        const float* xp = &x[(((size_t)(n * TSTEPS + t1) * HH + y) * WW + xx) * NCIN];
        float f0, f1, f2 = xp[2];
        if (t1 < INPUT_FRAMES) { f0 = xp[0]; f1 = xp[1]; }
        else { f0 = o0; f1 = o1; }
        size_t fb = ((size_t)(n * 3 + 0) * PR + y + 1) * PC + xx + 1;
        feed[fb] = f0;
        feed[fb + PHW] = f1;
        feed[fb + 2 * (size_t)PHW] = f2;
    }
}

// ---------------- nino prediction ----------------
__global__ void k_nino(const float* __restrict__ outbuf, float* __restrict__ pred) {
    int tidx = threadIdx.x;
    if (tidx >= 16 * 24) return;
    int j = tidx % 24;
    int n = tidx / 24;
    float acc = 0.f;
    for (int f = j; f < j + 3; ++f) {
        int t = 11 + f;
        const float* p = &outbuf[(((size_t)n * TSTEPS + t) * NCOUT + 0) * SS];
        float sloc = 0.f;
        for (int y = 10; y <= 12; ++y)
            for (int x = 19; x <= 29; ++x)
                sloc += p[y * WW + x];
        acc += sloc * (1.f / 33.f);
    }
    pred[n * 24 + j] = acc * (1.f / 3.f);
}

extern "C" void kernel_launch(void* const* d_in, const int* in_sizes, int n_in,
                              void* d_out, int out_size, void* d_ws, size_t ws_size,
                              hipStream_t stream) {
    const float* x      = (const float*)d_in[0];
    const float* conv_w = (const float*)d_in[1];
    const float* conv_b = (const float*)d_in[2];
    const float* h_w    = (const float*)d_in[3];
    const float* h_b    = (const float*)d_in[4];
    const float* m_w    = (const float*)d_in[5];
    const float* m_b    = (const float*)d_in[6];
    const float* z_w    = (const float*)d_in[7];
    const float* z_b    = (const float*)d_in[8];
    const float* o_w    = (const float*)d_in[9];
    const float* o_b    = (const float*)d_in[10];
    const float* out_w  = (const float*)d_in[11];
    const float* out_b  = (const float*)d_in[12];

    float* ws   = (float*)d_ws;
    float* hA   = ws + OFF_H;      // post-LSTM h (padded)
    float* c    = ws + OFF_C;
    float* m    = ws + OFF_M;
    float* feed = ws + OFF_FEED;
    float* Zb   = ws + OFF_Z;
    float* qkv  = ws + OFF_QKV;
    float* mkv  = ws + OFF_MKV;
    float* hB   = ws + OFF_HB;     // carry h (padded)
    float* iog  = ws + OFF_IOG;
    float* w2g  = ws + OFF_W2G;
    float* b2p  = ws + OFF_B2P;
    float* w3g  = ws + OFF_W3G;
    float* outp = (float*)d_out;

    k_zero<<<4058, 256, 0, stream>>>(ws, 1038688);                 // hA,c,m,feed,Z
    k_zero<<<1352, 256, 0, stream>>>(ws + OFF_HB, 346112);         // hB
    k_prep_w2g<<<722, 256, 0, stream>>>(conv_w, conv_b, w2g, b2p);
    k_prep_w3g<<<540, 256, 0, stream>>>(o_w, w3g);
    k_feed0<<<216, 256, 0, stream>>>(x, feed);

    for (int t = 0; t < TSTEPS; ++t) {
        k_conv_lstm<<<dim3(48, 16), 192, 0, stream>>>(feed, hB, w2g, b2p, c, hA);
        k_qkv<<<dim3(72, 10), 256, 0, stream>>>(hA, m, h_w, h_b, m_w, m_b, qkv, mkv);
        k_attn<<<dim3(36, 16), 256, 0, stream>>>(qkv, mkv, z_w, z_b, Zb);
        k_conv3x3<<<dim3(48, 12), 192, 0, stream>>>(Zb, DATT, hA, HD, w3g, o_b,
                                                    iog, 3 * HD);
        k_sa_gates<<<4608, 256, 0, stream>>>(iog, m, hB);
        k_out_feed<<<72, 256, 0, stream>>>(hB, out_w, out_b, x, outp, feed, t);
    }
    k_nino<<<1, 384, 0, stream>>>(outp, outp + (size_t)NB * TSTEPS * NCOUT * SS);
}

// Round 13
// 8847.671 us; speedup vs baseline: 1.4136x; 1.2707x over previous
//
#include <hip/hip_runtime.h>
#include <math.h>

#define HD 64
#define DATT 16
#define NCIN 3
#define NCOUT 2
#define HH 24
#define WW 48
#define SS (HH*WW)          // 1152
#define NB 16
#define TSTEPS 37
#define INPUT_FRAMES 12

#define PR 26
#define PC 52
#define PHW (PR*PC)         // 1352

// ---------------- workspace layout (floats) ----------------
#define OFF_H     0                      // hA: post-LSTM h (padded)
#define OFF_C     1384448
#define OFF_M     2564096
#define OFF_FEED  3743744
#define OFF_Z     3808640
#define ZERO_END  4154752                // zeroed each launch (1038688 f4)
#define OFF_QKV   4154752
#define OFF_MKV   5039488
#define OFF_HB    5629312                // hB: carry h (padded), zero-init separately
#define OFF_IOG   8873344
#define OFF_W2G   12412288               // 32*80*9*8 = 184320 (gate conv, oc-permuted)
#define OFF_B2P   12596608               // 256
#define OFF_BF    12596864               // B fragments for MFMA out conv: 282624 ushort = 141312 floats
// end = 12738176 floats = 50.95 MB

typedef __attribute__((ext_vector_type(8))) short short8;
typedef __attribute__((ext_vector_type(4))) float f32x4;

__device__ __forceinline__ float sigmoidf_(float x) {
    return 1.0f / (1.0f + __expf(-x));
}
__device__ __forceinline__ unsigned short f2bf(float f) {
    unsigned u = __float_as_uint(f);
    unsigned r = (u + 0x7fffu + ((u >> 16) & 1u)) >> 16;
    return (unsigned short)r;
}
__device__ __forceinline__ float bf2f(unsigned short b) {
    return __uint_as_float(((unsigned)b) << 16);
}

__global__ void k_zero(float* __restrict__ p, int n4) {
    int i = blockIdx.x * blockDim.x + threadIdx.x;
    if (i < n4) ((float4*)p)[i] = make_float4(0.f, 0.f, 0.f, 0.f);
}

// ---- weight reorder: conv_w -> w2g [ocg(32)][c(80)][kt(9)][ocl(8)], oc PERMUTED (r12) ----
__global__ void k_prep_w2g(const float* __restrict__ cw, const float* __restrict__ cb,
                           float* __restrict__ w2g, float* __restrict__ b2p) {
    int idx = blockIdx.x * blockDim.x + threadIdx.x;
    if (idx < 184320) {
        int ocl = idx & 7;
        int kt  = (idx >> 3) % 9;
        int c   = (idx / 72) % 80;
        int ocg = idx / 5760;
        int ocp_ = ocg * 8 + ocl;
        int oc_orig = ((ocp_ & 3) << 6) + (ocp_ >> 2);
        w2g[idx] = (c < 67) ? cw[oc_orig * 603 + c * 9 + kt] : 0.f;
    } else if (idx < 184576) {
        int ocp_ = idx - 184320;
        b2p[ocp_] = cb[((ocp_ & 3) << 6) + (ocp_ >> 2)];
    }
}

// ---- B fragment prep for MFMA out conv ----
// Bbuf[p(2)][nt(12)][ki(23)][lane(64)][j(8)] bf16; k = ki*32 + (lane>>4)*8 + j (kt-major: k = kt*80+c)
// n = nt*16 + (lane&15). p=0: bf16 hi of w; p=1: bf16 lo. k>=720 -> 0.
__global__ void k_prep_bf(const float* __restrict__ ow, unsigned short* __restrict__ bbuf) {
    int idx = blockIdx.x * 256 + threadIdx.x;
    if (idx >= 282624) return;
    int j    = idx & 7;
    int lane = (idx >> 3) & 63;
    int ki   = (idx >> 9) % 23;
    int nt   = (idx / 11776) % 12;
    int p    = idx / 141312;
    int k = ki * 32 + (lane >> 4) * 8 + j;
    int ncol = nt * 16 + (lane & 15);
    unsigned short v = 0;
    if (k < 720) {
        int c = k % 80, kt = k / 80;
        float w = ow[ncol * 720 + c * 9 + kt];
        unsigned short hi = f2bf(w);
        v = (p == 0) ? hi : f2bf(w - bf2f(hi));
    }
    bbuf[idx] = v;
}

// ---------------- initial feed (t=0) ----------------
__global__ void k_feed0(const float* __restrict__ x, float* __restrict__ feed) {
    int i = blockIdx.x * blockDim.x + threadIdx.x;
    if (i >= NB * 3 * SS) return;
    int s = i % SS;
    int ch = (i / SS) % 3;
    int n = i / (3 * SS);
    int y = s / WW, xx = s % WW;
    float v = x[(((size_t)(n * TSTEPS + 0) * HH + y) * WW + xx) * NCIN + ch];
    feed[((size_t)(n * 3 + ch) * PR + (y + 1)) * PC + (xx + 1)] = v;
}

// ---------------- gate conv 3x3 + FUSED LSTM gates (r12-verbatim, passing) ----------------
__global__ __launch_bounds__(192) void k_conv_lstm(
    const float* __restrict__ feed, const float* __restrict__ hin,
    const float* __restrict__ w, const float* __restrict__ b,
    float* __restrict__ c, float* __restrict__ hout)
{
    __shared__ __align__(16) float lds_patch[16 * 520];

    const int bx = blockIdx.x;
    const int n = bx / 3, tile = bx % 3;
    const int ocp = blockIdx.y;
    const int tid = threadIdx.x;
    const int y0 = tile * 8;

    const int wgsz = 5 * 16 * 72;
    const float* wg0 = w + (size_t)(ocp * 2) * wgsz;
    const float* wg1 = wg0 + wgsz;

    const float4* in1_4 = (const float4*)(feed + (size_t)n * 3 * PHW);
    const float4* in2_4 = (const float4*)(hin + (size_t)n * HD * PHW);

    float4 pf[11];
    auto load_chunk = [&](int chunk) {
#pragma unroll
        for (int k = 0; k < 11; ++k) {
            int i = tid + 192 * k;
            if (i < 2080) {
                int c_l = i / 130;
                int rem = i - c_l * 130;
                int cc = chunk * 16 + c_l;
                float4 v = make_float4(0.f, 0.f, 0.f, 0.f);
                if (cc < 67) {
                    v = (cc < 3) ? in1_4[(cc * PR + y0) * 13 + rem]
                                 : in2_4[((cc - 3) * PR + y0) * 13 + rem];
                }
                pf[k] = v;
            }
        }
    };

    const int cg = tid % 24;
    const int ty = tid / 24;
    const int x0 = cg * 2;
    const int y_out = y0 + ty;

    float acc[32];
#pragma unroll
    for (int j = 0; j < 32; ++j) acc[j] = 0.f;

    load_chunk(0);
    for (int chunk = 0; chunk < 5; ++chunk) {
        __syncthreads();
#pragma unroll
        for (int k = 0; k < 11; ++k) {
            int i = tid + 192 * k;
            if (i < 2080) ((float4*)lds_patch)[i] = pf[k];
        }
        if (chunk + 1 < 5) load_chunk(chunk + 1);
        __syncthreads();

        for (int icl = 0; icl < 16; ++icl) {
            const int cc = chunk * 16 + icl;
            const float* wb0 = wg0 + cc * 72;
            const float* wb1 = wg1 + cc * 72;
            const float* pr = &lds_patch[icl * 520 + ty * PC + x0];
#pragma unroll
            for (int ky = 0; ky < 3; ++ky) {
                const float* r = pr + ky * PC;
                float i0 = r[0], i1 = r[1], i2 = r[2], i3 = r[3];
                const float* wk0 = wb0 + ky * 24;
                const float* wk1 = wb1 + ky * 24;
#pragma unroll
                for (int kx = 0; kx < 3; ++kx) {
                    float va = (kx == 0) ? i0 : ((kx == 1) ? i1 : i2);
                    float vb = (kx == 0) ? i1 : ((kx == 1) ? i2 : i3);
                    const float4 wa0  = *(const float4*)(wk0 + kx * 8);
                    const float4 wb40 = *(const float4*)(wk0 + kx * 8 + 4);
                    const float4 wa1  = *(const float4*)(wk1 + kx * 8);
                    const float4 wb41 = *(const float4*)(wk1 + kx * 8 + 4);
                    acc[0]  += va * wa0.x;  acc[1]  += va * wa0.y;
                    acc[2]  += va * wa0.z;  acc[3]  += va * wa0.w;
                    acc[4]  += va * wb40.x; acc[5]  += va * wb40.y;
                    acc[6]  += va * wb40.z; acc[7]  += va * wb40.w;
                    acc[8]  += vb * wa0.x;  acc[9]  += vb * wa0.y;
                    acc[10] += vb * wa0.z;  acc[11] += vb * wa0.w;
                    acc[12] += vb * wb40.x; acc[13] += vb * wb40.y;
                    acc[14] += vb * wb40.z; acc[15] += vb * wb40.w;
                    acc[16] += va * wa1.x;  acc[17] += va * wa1.y;
                    acc[18] += va * wa1.z;  acc[19] += va * wa1.w;
                    acc[20] += va * wb41.x; acc[21] += va * wb41.y;
                    acc[22] += va * wb41.z; acc[23] += va * wb41.w;
                    acc[24] += vb * wa1.x;  acc[25] += vb * wa1.y;
                    acc[26] += vb * wa1.z;  acc[27] += vb * wa1.w;
                    acc[28] += vb * wb41.x; acc[29] += vb * wb41.y;
                    acc[30] += vb * wb41.z; acc[31] += vb * wb41.w;
                }
            }
        }
    }

    const float* bb = b + ocp * 16;
#pragma unroll
    for (int chl = 0; chl < 4; ++chl) {
        const int ch = ocp * 4 + chl;
#pragma unroll
        for (int px = 0; px < 2; ++px) {
            const int base = chl * 4 + 8 * px + ((chl >= 2) ? 8 : 0);
            float iv = sigmoidf_(acc[base]     + bb[chl * 4 + 0]);
            float fv = sigmoidf_(acc[base + 1] + bb[chl * 4 + 1]);
            float ov = sigmoidf_(acc[base + 2] + bb[chl * 4 + 2]);
            float gv = tanhf    (acc[base + 3] + bb[chl * 4 + 3]);
            size_t ci_ = ((size_t)(n * HD + ch) * HH + y_out) * WW + x0 + px;
            float cn = fv * c[ci_] + iv * gv;
            c[ci_] = cn;
            hout[((size_t)(n * HD + ch) * PR + y_out + 1) * PC + x0 + px + 1] = ov * tanhf(cn);
        }
    }
}

// ---------------- MFMA out conv: split-bf16 implicit GEMM ----------------
// grid (24 y, 2 nb, 16 n); block 192 = 3 waves; wave = Mtile (16 x-cols), 6 Ntiles each.
// A patch in LDS as (lo<<16|hi) bf16-pair dwords, layout [pr(3)][pc(52)][c(stride 81)].
// K = kt*80 + c (720, padded to 736); C = Ahi*Bhi + Ahi*Blo + Alo*Bhi (fp32-accurate).
#define ZOFF (3*52*81)
__global__ __launch_bounds__(192) void k_conv_mfma(
    const float* __restrict__ Zin, const float* __restrict__ hin,
    const unsigned short* __restrict__ bbuf, const float* __restrict__ ob,
    float* __restrict__ iog)
{
    __shared__ int lds[3 * 52 * 81 + 8];
    const int y0 = blockIdx.x;
    const int nb = blockIdx.y;
    const int n  = blockIdx.z;
    const int tid = threadIdx.x;

    // stage A patch (hi/lo packed)
    const float* zbase = Zin + (size_t)n * DATT * PHW;
    const float* hbase = hin + (size_t)n * HD * PHW;
    for (int e = tid; e < 12480; e += 192) {
        int c = e / 156;
        int r2 = e - c * 156;
        int pr = r2 / 52, pc = r2 - pr * 52;
        const float* src = (c < 16) ? (zbase + (size_t)c * PHW)
                                    : (hbase + (size_t)(c - 16) * PHW);
        float f = src[(y0 + pr) * PC + pc];
        unsigned short hi = f2bf(f);
        unsigned short lo = f2bf(f - bf2f(hi));
        lds[(pr * 52 + pc) * 81 + c] = ((unsigned)lo << 16) | (unsigned)hi;
    }
    if (tid < 8) lds[ZOFF + tid] = 0;
    __syncthreads();

    const int wv = tid >> 6;
    const int lane = tid & 63;
    const int mcol = lane & 15;
    const int quad = lane >> 4;
    const int x = wv * 16 + mcol;       // A m-index (output column)

    f32x4 acc[6];
#pragma unroll
    for (int t = 0; t < 6; ++t) acc[t] = (f32x4){0.f, 0.f, 0.f, 0.f};

    const unsigned short* bb = bbuf + (size_t)(nb * 6) * 23 * 512;

    for (int ki = 0; ki < 23; ++ki) {
        int k0 = ki * 32 + quad * 8;
        int abase;
        if (k0 < 720) {
            int kt = k0 / 80;
            int c0 = k0 - kt * 80;
            int dy = kt / 3, dx = kt - dy * 3;
            abase = (dy * 52 + x + dx) * 81 + c0;
        } else {
            abase = ZOFF;
        }
        int d0 = lds[abase + 0], d1 = lds[abase + 1];
        int d2 = lds[abase + 2], d3 = lds[abase + 3];
        int d4 = lds[abase + 4], d5 = lds[abase + 5];
        int d6 = lds[abase + 6], d7 = lds[abase + 7];
        union { int i[4]; short8 v; } ah, al;
        ah.i[0] = (d1 << 16) | (d0 & 0xffff);
        ah.i[1] = (d3 << 16) | (d2 & 0xffff);
        ah.i[2] = (d5 << 16) | (d4 & 0xffff);
        ah.i[3] = (d7 << 16) | (d6 & 0xffff);
        al.i[0] = (d1 & 0xffff0000) | ((unsigned)d0 >> 16);
        al.i[1] = (d3 & 0xffff0000) | ((unsigned)d2 >> 16);
        al.i[2] = (d5 & 0xffff0000) | ((unsigned)d4 >> 16);
        al.i[3] = (d7 & 0xffff0000) | ((unsigned)d6 >> 16);

#pragma unroll
        for (int nt = 0; nt < 6; ++nt) {
            const unsigned short* bhp = bb + ((size_t)nt * 23 + ki) * 512 + lane * 8;
            const unsigned short* blp = bhp + (size_t)12 * 23 * 512;
            short8 bh = *(const short8*)bhp;
            short8 bl = *(const short8*)blp;
            acc[nt] = __builtin_amdgcn_mfma_f32_16x16x32_bf16(ah.v, bh, acc[nt], 0, 0, 0);
            acc[nt] = __builtin_amdgcn_mfma_f32_16x16x32_bf16(ah.v, bl, acc[nt], 0, 0, 0);
            acc[nt] = __builtin_amdgcn_mfma_f32_16x16x32_bf16(al.v, bh, acc[nt], 0, 0, 0);
        }
    }

    // epilogue: D[m = quad*4+reg][nOut = lane&15 within tile]
    const int sbase = y0 * 48 + wv * 16 + quad * 4;
#pragma unroll
    for (int nt = 0; nt < 6; ++nt) {
        int oc = nb * 96 + nt * 16 + mcol;
        float bv = ob[oc];
        float* dst = iog + ((size_t)n * 192 + oc) * 1152 + sbase;
#pragma unroll
        for (int r = 0; r < 4; ++r) dst[r] = acc[nt][r] + bv;
    }
}

// ---------------- 1x1 q/k/v + mk/mv projections ----------------
__global__ __launch_bounds__(256) void k_qkv(
    const float* __restrict__ h, const float* __restrict__ m,
    const float* __restrict__ hw, const float* __restrict__ hb,
    const float* __restrict__ mw, const float* __restrict__ mb,
    float* __restrict__ qkv, float* __restrict__ mkv) {
    __shared__ float lw[512];
    __shared__ float lb[8];
    const int g = blockIdx.y;
    const int tid = threadIdx.x;
    const float* wsrc = (g < 6) ? (hw + g * 512) : (mw + (g - 6) * 512);
    const float* bsrc = (g < 6) ? (hb + g * 8) : (mb + (g - 6) * 8);
    for (int i = tid; i < 512; i += 256) lw[i] = wsrc[i];
    if (tid < 8) lb[tid] = bsrc[tid];
    __syncthreads();

    int idx = blockIdx.x * 256 + tid;
    int s = idx % SS;
    int n = idx / SS;
    int y = s / WW, x = s % WW;

    float reg[HD];
    if (g < 6) {
        const float* src = h + (size_t)n * HD * PHW + (y + 1) * PC + (x + 1);
#pragma unroll
        for (int ic = 0; ic < HD; ++ic) reg[ic] = src[ic * PHW];
    } else {
        const float* src = m + (size_t)n * HD * SS + s;
#pragma unroll
        for (int ic = 0; ic < HD; ++ic) reg[ic] = src[ic * SS];
    }

    float* dst = (g < 6) ? &qkv[((size_t)n * SS + s) * 48 + g * 8]
                         : &mkv[((size_t)n * SS + s) * 32 + (g - 6) * 8];
#pragma unroll
    for (int j = 0; j < 8; ++j) {
        const float* wr = &lw[j * HD];
        float a = lb[j];
#pragma unroll
        for (int ic = 0; ic < HD; ++ic) a += reg[ic] * wr[ic];
        dst[j] = a;
    }
}

#define LOAD16(dst, srcp) do {                       \
    float4 _a = ((const float4*)(srcp))[0];          \
    float4 _b = ((const float4*)(srcp))[1];          \
    float4 _c = ((const float4*)(srcp))[2];          \
    float4 _d = ((const float4*)(srcp))[3];          \
    dst[0]=_a.x; dst[1]=_a.y; dst[2]=_a.z; dst[3]=_a.w;   \
    dst[4]=_b.x; dst[5]=_b.y; dst[6]=_b.z; dst[7]=_b.w;   \
    dst[8]=_c.x; dst[9]=_c.y; dst[10]=_c.z; dst[11]=_c.w; \
    dst[12]=_d.x; dst[13]=_d.y; dst[14]=_d.z; dst[15]=_d.w; } while(0)

// ---------------- dual spatial attention + z 1x1 (r8-verbatim) ----------------
#define TSTRIDE 68
__global__ __launch_bounds__(256) void k_attn(
    const float* __restrict__ qkv, const float* __restrict__ mkv,
    const float* __restrict__ zw, const float* __restrict__ zb,
    float* __restrict__ Z)
{
    __shared__ __align__(16) float smem[144 * TSTRIDE];
    const int n = blockIdx.y;
    const int tid = threadIdx.x;
    const int rowthr = tid >> 4;
    const int part = tid & 15;
    const int s0 = blockIdx.x * 32 + rowthr * 2;

    float q0[16], q1[16];
    LOAD16(q0, &qkv[((size_t)n * SS + s0) * 48]);
    LOAD16(q1, &qkv[((size_t)n * SS + s0 + 1) * 48]);

    float lh0 = 0.f, lh1 = 0.f, lm0 = 0.f, lm1 = 0.f;
    float oh0[16], oh1[16], om0[16], om1[16];
#pragma unroll
    for (int j = 0; j < 16; ++j) { oh0[j] = 0.f; oh1[j] = 0.f; om0[j] = 0.f; om1[j] = 0.f; }

    const float4* qkv4 = (const float4*)qkv + (size_t)n * SS * 12;
    const float4* mkv4 = (const float4*)mkv + (size_t)n * SS * 8;

    for (int tile = 0; tile < 8; ++tile) {
        __syncthreads();
#pragma unroll
        for (int k = 0; k < 9; ++k) {
            int j = tid + 256 * k;
            int t_loc = j >> 4, f = j & 15;
            int t = tile * 144 + t_loc;
            float4 v;
            if (f < 8) v = qkv4[t * 12 + 4 + f];
            else       v = mkv4[t * 8 + (f - 8)];
            *(float4*)&smem[t_loc * TSTRIDE + f * 4] = v;
        }
        __syncthreads();

        const int t0 = part * 9;
        for (int tl = t0; tl < t0 + 9; ++tl) {
            const float* kvb = &smem[tl * TSTRIDE];
            float kk[16], vv[16];
            LOAD16(kk, kvb);
            float d0 = 0.f, d1 = 0.f;
#pragma unroll
            for (int j = 0; j < 16; ++j) { d0 += q0[j] * kk[j]; d1 += q1[j] * kk[j]; }
            float e0 = __expf(d0 * 0.25f), e1 = __expf(d1 * 0.25f);
            lh0 += e0; lh1 += e1;
            LOAD16(vv, kvb + 16);
#pragma unroll
            for (int j = 0; j < 16; ++j) { oh0[j] += e0 * vv[j]; oh1[j] += e1 * vv[j]; }
            LOAD16(kk, kvb + 32);
            float f0 = 0.f, f1 = 0.f;
#pragma unroll
            for (int j = 0; j < 16; ++j) { f0 += q0[j] * kk[j]; f1 += q1[j] * kk[j]; }
            float g0 = __expf(f0 * 0.25f), g1 = __expf(f1 * 0.25f);
            lm0 += g0; lm1 += g1;
            LOAD16(vv, kvb + 48);
#pragma unroll
            for (int j = 0; j < 16; ++j) { om0[j] += g0 * vv[j]; om1[j] += g1 * vv[j]; }
        }
    }

#pragma unroll
    for (int mask = 1; mask <= 8; mask <<= 1) {
        lh0 += __shfl_xor(lh0, mask, 16);
        lh1 += __shfl_xor(lh1, mask, 16);
        lm0 += __shfl_xor(lm0, mask, 16);
        lm1 += __shfl_xor(lm1, mask, 16);
#pragma unroll
        for (int j = 0; j < 16; ++j) {
            oh0[j] += __shfl_xor(oh0[j], mask, 16);
            oh1[j] += __shfl_xor(oh1[j], mask, 16);
            om0[j] += __shfl_xor(om0[j], mask, 16);
            om1[j] += __shfl_xor(om1[j], mask, 16);
        }
    }

    const int zc = part;
    const float* zr = &zw[zc * 32];
    float zrh[16], zrm[16];
    LOAD16(zrh, zr);
    LOAD16(zrm, zr + 16);
    float zbv = zb[zc];
    float ilh0 = 1.f / lh0, ilh1 = 1.f / lh1;
    float ilm0 = 1.f / lm0, ilm1 = 1.f / lm1;
    float a0 = zbv, a1 = zbv;
#pragma unroll
    for (int j = 0; j < 16; ++j) {
        a0 += zrh[j] * (oh0[j] * ilh0) + zrm[j] * (om0[j] * ilm0);
        a1 += zrh[j] * (oh1[j] * ilh1) + zrm[j] * (om1[j] * ilm1);
    }
    {
        int y0_ = s0 / WW, x0_ = s0 % WW;
        Z[((size_t)(n * DATT + zc) * PR + y0_ + 1) * PC + x0_ + 1] = a0;
        int y1_ = (s0 + 1) / WW, x1_ = (s0 + 1) % WW;
        Z[((size_t)(n * DATT + zc) * PR + y1_ + 1) * PC + x1_ + 1] = a1;
    }
}

// ---------------- SA memory gates (writes carry h = hB, padded) ----------------
__global__ void k_sa_gates(const float* __restrict__ iog, float* __restrict__ m,
                           float* __restrict__ h) {
    int i = blockIdx.x * blockDim.x + threadIdx.x;
    if (i >= NB * HD * SS) return;
    int s = i % SS;
    int ch = (i / SS) % HD;
    int n = i / (HD * SS);
    const float* ib = iog + (size_t)n * 3 * HD * SS;
    float si = ib[ch * SS + s];
    float sg = ib[(HD + ch) * SS + s];
    float so = ib[(2 * HD + ch) * SS + s];
    si = sigmoidf_(si);
    sg = tanhf(sg);
    float mn = si * sg + (1.f - si) * m[i];
    m[i] = mn;
    int y = s / WW, x = s % WW;
    h[((size_t)(n * HD + ch) * PR + (y + 1)) * PC + (x + 1)] = sigmoidf_(so) * mn;
}

// ---------------- out 1x1 (64->2) + next-step feed, fused ----------------
__global__ void k_out_feed(const float* __restrict__ h, const float* __restrict__ ow,
                           const float* __restrict__ ob, const float* __restrict__ x,
                           float* __restrict__ outbuf, float* __restrict__ feed, int t) {
    int idx = blockIdx.x * 256 + threadIdx.x;
    if (idx >= NB * SS) return;
    int s = idx % SS;
    int n = idx / SS;
    int y = s / WW, xx = s % WW;
    const float* src = h + (size_t)n * HD * PHW + (y + 1) * PC + (xx + 1);
    float o0 = ob[0], o1 = ob[1];
#pragma unroll
    for (int ic = 0; ic < HD; ++ic) {
        float r = src[ic * PHW];
        o0 += r * ow[ic];
        o1 += r * ow[HD + ic];
    }
    outbuf[(((size_t)n * TSTEPS + t) * NCOUT + 0) * SS + s] = o0;
    outbuf[(((size_t)n * TSTEPS + t) * NCOUT + 1) * SS + s] = o1;

    if (t + 1 < TSTEPS) {
        int t1 = t + 1;
        const float* xp = &x[(((size_t)(n * TSTEPS + t1) * HH + y) * WW + xx) * NCIN];
        float f0, f1, f2 = xp[2];
        if (t1 < INPUT_FRAMES) { f0 = xp[0]; f1 = xp[1]; }
        else { f0 = o0; f1 = o1; }
        size_t fb = ((size_t)(n * 3 + 0) * PR + y + 1) * PC + xx + 1;
        feed[fb] = f0;
        feed[fb + PHW] = f1;
        feed[fb + 2 * (size_t)PHW] = f2;
    }
}

// ---------------- nino prediction ----------------
__global__ void k_nino(const float* __restrict__ outbuf, float* __restrict__ pred) {
    int tidx = threadIdx.x;
    if (tidx >= 16 * 24) return;
    int j = tidx % 24;
    int n = tidx / 24;
    float acc = 0.f;
    for (int f = j; f < j + 3; ++f) {
        int t = 11 + f;
        const float* p = &outbuf[(((size_t)n * TSTEPS + t) * NCOUT + 0) * SS];
        float sloc = 0.f;
        for (int y = 10; y <= 12; ++y)
            for (int x = 19; x <= 29; ++x)
                sloc += p[y * WW + x];
        acc += sloc * (1.f / 33.f);
    }
    pred[n * 24 + j] = acc * (1.f / 3.f);
}

extern "C" void kernel_launch(void* const* d_in, const int* in_sizes, int n_in,
                              void* d_out, int out_size, void* d_ws, size_t ws_size,
                              hipStream_t stream) {
    const float* x      = (const float*)d_in[0];
    const float* conv_w = (const float*)d_in[1];
    const float* conv_b = (const float*)d_in[2];
    const float* h_w    = (const float*)d_in[3];
    const float* h_b    = (const float*)d_in[4];
    const float* m_w    = (const float*)d_in[5];
    const float* m_b    = (const float*)d_in[6];
    const float* z_w    = (const float*)d_in[7];
    const float* z_b    = (const float*)d_in[8];
    const float* o_w    = (const float*)d_in[9];
    const float* o_b    = (const float*)d_in[10];
    const float* out_w  = (const float*)d_in[11];
    const float* out_b  = (const float*)d_in[12];

    float* ws   = (float*)d_ws;
    float* hA   = ws + OFF_H;
    float* c    = ws + OFF_C;
    float* m    = ws + OFF_M;
    float* feed = ws + OFF_FEED;
    float* Zb   = ws + OFF_Z;
    float* qkv  = ws + OFF_QKV;
    float* mkv  = ws + OFF_MKV;
    float* hB   = ws + OFF_HB;
    float* iog  = ws + OFF_IOG;
    float* w2g  = ws + OFF_W2G;
    float* b2p  = ws + OFF_B2P;
    unsigned short* bbuf = (unsigned short*)(ws + OFF_BF);
    float* outp = (float*)d_out;

    k_zero<<<4058, 256, 0, stream>>>(ws, 1038688);                 // hA,c,m,feed,Z
    k_zero<<<1352, 256, 0, stream>>>(ws + OFF_HB, 346112);         // hB
    k_prep_w2g<<<722, 256, 0, stream>>>(conv_w, conv_b, w2g, b2p);
    k_prep_bf<<<1104, 256, 0, stream>>>(o_w, bbuf);
    k_feed0<<<216, 256, 0, stream>>>(x, feed);

    for (int t = 0; t < TSTEPS; ++t) {
        k_conv_lstm<<<dim3(48, 16), 192, 0, stream>>>(feed, hB, w2g, b2p, c, hA);
        k_qkv<<<dim3(72, 10), 256, 0, stream>>>(hA, m, h_w, h_b, m_w, m_b, qkv, mkv);
        k_attn<<<dim3(36, 16), 256, 0, stream>>>(qkv, mkv, z_w, z_b, Zb);
        k_conv_mfma<<<dim3(24, 2, 16), 192, 0, stream>>>(Zb, hA, bbuf, o_b, iog);
        k_sa_gates<<<4608, 256, 0, stream>>>(iog, m, hB);
        k_out_feed<<<72, 256, 0, stream>>>(hB, out_w, out_b, x, outp, feed, t);
    }
    k_nino<<<1, 384, 0, stream>>>(outp, outp + (size_t)NB * TSTEPS * NCOUT * SS);
}

// Round 14
// 7144.888 us; speedup vs baseline: 1.7505x; 1.2383x over previous
//
#include <hip/hip_runtime.h>
#include <math.h>

#define HD 64
#define DATT 16
#define NCIN 3
#define NCOUT 2
#define HH 24
#define WW 48
#define SS (HH*WW)          // 1152
#define NB 16
#define TSTEPS 37
#define INPUT_FRAMES 12

#define PR 26
#define PC 52
#define PHW (PR*PC)         // 1352

// ---------------- workspace layout (floats) ----------------
#define OFF_H     0                      // hA: post-LSTM h (padded)
#define OFF_C     1384448
#define OFF_M     2564096
#define OFF_FEED  3743744
#define OFF_Z     3808640
#define ZERO_END  4154752                // zeroed each launch (1038688 f4)
#define OFF_QKV   4154752
#define OFF_MKV   5039488
#define OFF_HB    5629312                // hB: carry h (padded), zero-init separately
#define OFF_IOG   8873344
#define OFF_BF2   12412288               // gate-conv B fragments: 344064 ushort = 172032 floats
#define OFF_BF    12596864               // out-conv B fragments: 282624 ushort = 141312 floats
// end = 12738176 floats = 50.95 MB

typedef __attribute__((ext_vector_type(8))) short short8;
typedef __attribute__((ext_vector_type(4))) float f32x4;

__device__ __forceinline__ float sigmoidf_(float x) {
    return 1.0f / (1.0f + __expf(-x));
}
__device__ __forceinline__ unsigned short f2bf(float f) {
    unsigned u = __float_as_uint(f);
    unsigned r = (u + 0x7fffu + ((u >> 16) & 1u)) >> 16;
    return (unsigned short)r;
}
__device__ __forceinline__ float bf2f(unsigned short b) {
    return __uint_as_float(((unsigned)b) << 16);
}

__global__ void k_zero(float* __restrict__ p, int n4) {
    int i = blockIdx.x * blockDim.x + threadIdx.x;
    if (i < n4) ((float4*)p)[i] = make_float4(0.f, 0.f, 0.f, 0.f);
}

// ---- B fragment prep for MFMA gate conv ----
// bbuf2[p(2)][nt(16)][ki(21)][lane(64)][j(8)] bf16; n = nt*16+(lane&15) = ORIGINAL oc;
// k = ki*32 + (lane>>4)*8 + j, kt-major: k = kt*72 + c (c>=67 or k>=648 -> 0).
__global__ void k_prep_bf2(const float* __restrict__ cw, unsigned short* __restrict__ bbuf) {
    int idx = blockIdx.x * 256 + threadIdx.x;
    if (idx >= 344064) return;
    int j    = idx & 7;
    int lane = (idx >> 3) & 63;
    int ki   = (idx >> 9) % 21;
    int nt   = (idx / 10752) % 16;
    int p    = idx / 172032;
    int k = ki * 32 + (lane >> 4) * 8 + j;
    int ncol = nt * 16 + (lane & 15);
    unsigned short v = 0;
    if (k < 648) {
        int c = k % 72, kt = k / 72;
        if (c < 67) {
            float w = cw[ncol * 603 + c * 9 + kt];
            unsigned short hi = f2bf(w);
            v = (p == 0) ? hi : f2bf(w - bf2f(hi));
        }
    }
    bbuf[idx] = v;
}

// ---- B fragment prep for MFMA out conv (r13-verbatim) ----
__global__ void k_prep_bf(const float* __restrict__ ow, unsigned short* __restrict__ bbuf) {
    int idx = blockIdx.x * 256 + threadIdx.x;
    if (idx >= 282624) return;
    int j    = idx & 7;
    int lane = (idx >> 3) & 63;
    int ki   = (idx >> 9) % 23;
    int nt   = (idx / 11776) % 12;
    int p    = idx / 141312;
    int k = ki * 32 + (lane >> 4) * 8 + j;
    int ncol = nt * 16 + (lane & 15);
    unsigned short v = 0;
    if (k < 720) {
        int c = k % 80, kt = k / 80;
        float w = ow[ncol * 720 + c * 9 + kt];
        unsigned short hi = f2bf(w);
        v = (p == 0) ? hi : f2bf(w - bf2f(hi));
    }
    bbuf[idx] = v;
}

// ---------------- initial feed (t=0) ----------------
__global__ void k_feed0(const float* __restrict__ x, float* __restrict__ feed) {
    int i = blockIdx.x * blockDim.x + threadIdx.x;
    if (i >= NB * 3 * SS) return;
    int s = i % SS;
    int ch = (i / SS) % 3;
    int n = i / (3 * SS);
    int y = s / WW, xx = s % WW;
    float v = x[(((size_t)(n * TSTEPS + 0) * HH + y) * WW + xx) * NCIN + ch];
    feed[((size_t)(n * 3 + ch) * PR + (y + 1)) * PC + (xx + 1)] = v;
}

// ---------------- MFMA gate conv + FUSED LSTM gates ----------------
// grid (24 y, 2 nb, 16 n); block 192 = 3 waves x 16 M. K = kt*72+c (648, pad 672).
// Block nb covers channels nb*32..nb*32+31 via 8 N-tiles nt = gate*4 + nb*2 + jg
// -> lane holds all 4 gates for its channel directly (no shuffles).
#define ZOFF2 (3*52*73)
__global__ __launch_bounds__(192) void k_conv_lstm_mfma(
    const float* __restrict__ feed, const float* __restrict__ hin,
    const unsigned short* __restrict__ bbuf, const float* __restrict__ cb,
    float* __restrict__ c, float* __restrict__ hout)
{
    __shared__ int lds[3 * 52 * 73 + 8];
    const int y0 = blockIdx.x;
    const int nb = blockIdx.y;
    const int n  = blockIdx.z;
    const int tid = threadIdx.x;

    const float* fbase = feed + (size_t)n * 3 * PHW;
    const float* hbase = hin + (size_t)n * HD * PHW;
    for (int e = tid; e < 11232; e += 192) {      // 72 ch x 3 rows x 52 cols
        int cc = e / 156;
        int r2 = e - cc * 156;
        int pr = r2 / 52, pc = r2 - pr * 52;
        float f = 0.f;
        if (cc < 67) {
            const float* src = (cc < 3) ? (fbase + (size_t)cc * PHW)
                                        : (hbase + (size_t)(cc - 3) * PHW);
            f = src[(y0 + pr) * PC + pc];
        }
        unsigned short hi = f2bf(f);
        unsigned short lo = f2bf(f - bf2f(hi));
        lds[(pr * 52 + pc) * 73 + cc] = ((unsigned)lo << 16) | (unsigned)hi;
    }
    if (tid < 8) lds[ZOFF2 + tid] = 0;
    __syncthreads();

    const int wv = tid >> 6;
    const int lane = tid & 63;
    const int mcol = lane & 15;
    const int quad = lane >> 4;
    const int x = wv * 16 + mcol;

    f32x4 acc[8];
#pragma unroll
    for (int t = 0; t < 8; ++t) acc[t] = (f32x4){0.f, 0.f, 0.f, 0.f};

    for (int ki = 0; ki < 21; ++ki) {
        int k0 = ki * 32 + quad * 8;
        int abase;
        if (k0 < 648) {
            int kt = k0 / 72;
            int c0 = k0 - kt * 72;
            int dy = kt / 3, dx = kt - dy * 3;
            abase = (dy * 52 + x + dx) * 73 + c0;
        } else {
            abase = ZOFF2;
        }
        int d0 = lds[abase + 0], d1 = lds[abase + 1];
        int d2 = lds[abase + 2], d3 = lds[abase + 3];
        int d4 = lds[abase + 4], d5 = lds[abase + 5];
        int d6 = lds[abase + 6], d7 = lds[abase + 7];
        union { int i[4]; short8 v; } ah, al;
        ah.i[0] = (d1 << 16) | (d0 & 0xffff);
        ah.i[1] = (d3 << 16) | (d2 & 0xffff);
        ah.i[2] = (d5 << 16) | (d4 & 0xffff);
        ah.i[3] = (d7 << 16) | (d6 & 0xffff);
        al.i[0] = (d1 & 0xffff0000) | ((unsigned)d0 >> 16);
        al.i[1] = (d3 & 0xffff0000) | ((unsigned)d2 >> 16);
        al.i[2] = (d5 & 0xffff0000) | ((unsigned)d4 >> 16);
        al.i[3] = (d7 & 0xffff0000) | ((unsigned)d6 >> 16);

#pragma unroll
        for (int t = 0; t < 8; ++t) {
            const int gate = t & 3, jg = t >> 2;
            const int nt = gate * 4 + nb * 2 + jg;
            const unsigned short* bhp = bbuf + ((size_t)nt * 21 + ki) * 512 + lane * 8;
            const unsigned short* blp = bhp + (size_t)172032;
            short8 bh = *(const short8*)bhp;
            short8 bl = *(const short8*)blp;
            acc[t] = __builtin_amdgcn_mfma_f32_16x16x32_bf16(ah.v, bh, acc[t], 0, 0, 0);
            acc[t] = __builtin_amdgcn_mfma_f32_16x16x32_bf16(ah.v, bl, acc[t], 0, 0, 0);
            acc[t] = __builtin_amdgcn_mfma_f32_16x16x32_bf16(al.v, bh, acc[t], 0, 0, 0);
        }
    }

    // fused LSTM epilogue: rows = spatial (quad*4+r), col = channel mcol
#pragma unroll
    for (int jg = 0; jg < 2; ++jg) {
        const int ch = (nb * 2 + jg) * 16 + mcol;
        const float bi = cb[ch], bfv = cb[64 + ch], bo = cb[128 + ch], bg = cb[192 + ch];
        const int xr = wv * 16 + quad * 4;
        size_t cb_ = ((size_t)(n * HD + ch) * HH + y0) * WW + xr;
        float4 cold = *(float4*)&c[cb_];
        float cn[4], hn[4];
#pragma unroll
        for (int r = 0; r < 4; ++r) {
            float iv = sigmoidf_(acc[jg * 4 + 0][r] + bi);
            float fv = sigmoidf_(acc[jg * 4 + 1][r] + bfv);
            float ov = sigmoidf_(acc[jg * 4 + 2][r] + bo);
            float gv = tanhf    (acc[jg * 4 + 3][r] + bg);
            float co = (r == 0) ? cold.x : (r == 1) ? cold.y : (r == 2) ? cold.z : cold.w;
            cn[r] = fv * co + iv * gv;
            hn[r] = ov * tanhf(cn[r]);
        }
        *(float4*)&c[cb_] = make_float4(cn[0], cn[1], cn[2], cn[3]);
        float* hp = &hout[((size_t)(n * HD + ch) * PR + y0 + 1) * PC + xr + 1];
        hp[0] = hn[0]; hp[1] = hn[1]; hp[2] = hn[2]; hp[3] = hn[3];
    }
}

// ---------------- MFMA out conv: split-bf16 implicit GEMM (r13-verbatim) ----------------
#define ZOFF (3*52*81)
__global__ __launch_bounds__(192) void k_conv_mfma(
    const float* __restrict__ Zin, const float* __restrict__ hin,
    const unsigned short* __restrict__ bbuf, const float* __restrict__ ob,
    float* __restrict__ iog)
{
    __shared__ int lds[3 * 52 * 81 + 8];
    const int y0 = blockIdx.x;
    const int nb = blockIdx.y;
    const int n  = blockIdx.z;
    const int tid = threadIdx.x;

    const float* zbase = Zin + (size_t)n * DATT * PHW;
    const float* hbase = hin + (size_t)n * HD * PHW;
    for (int e = tid; e < 12480; e += 192) {
        int c = e / 156;
        int r2 = e - c * 156;
        int pr = r2 / 52, pc = r2 - pr * 52;
        const float* src = (c < 16) ? (zbase + (size_t)c * PHW)
                                    : (hbase + (size_t)(c - 16) * PHW);
        float f = src[(y0 + pr) * PC + pc];
        unsigned short hi = f2bf(f);
        unsigned short lo = f2bf(f - bf2f(hi));
        lds[(pr * 52 + pc) * 81 + c] = ((unsigned)lo << 16) | (unsigned)hi;
    }
    if (tid < 8) lds[ZOFF + tid] = 0;
    __syncthreads();

    const int wv = tid >> 6;
    const int lane = tid & 63;
    const int mcol = lane & 15;
    const int quad = lane >> 4;
    const int x = wv * 16 + mcol;

    f32x4 acc[6];
#pragma unroll
    for (int t = 0; t < 6; ++t) acc[t] = (f32x4){0.f, 0.f, 0.f, 0.f};

    const unsigned short* bb = bbuf + (size_t)(nb * 6) * 23 * 512;

    for (int ki = 0; ki < 23; ++ki) {
        int k0 = ki * 32 + quad * 8;
        int abase;
        if (k0 < 720) {
            int kt = k0 / 80;
            int c0 = k0 - kt * 80;
            int dy = kt / 3, dx = kt - dy * 3;
            abase = (dy * 52 + x + dx) * 81 + c0;
        } else {
            abase = ZOFF;
        }
        int d0 = lds[abase + 0], d1 = lds[abase + 1];
        int d2 = lds[abase + 2], d3 = lds[abase + 3];
        int d4 = lds[abase + 4], d5 = lds[abase + 5];
        int d6 = lds[abase + 6], d7 = lds[abase + 7];
        union { int i[4]; short8 v; } ah, al;
        ah.i[0] = (d1 << 16) | (d0 & 0xffff);
        ah.i[1] = (d3 << 16) | (d2 & 0xffff);
        ah.i[2] = (d5 << 16) | (d4 & 0xffff);
        ah.i[3] = (d7 << 16) | (d6 & 0xffff);
        al.i[0] = (d1 & 0xffff0000) | ((unsigned)d0 >> 16);
        al.i[1] = (d3 & 0xffff0000) | ((unsigned)d2 >> 16);
        al.i[2] = (d5 & 0xffff0000) | ((unsigned)d4 >> 16);
        al.i[3] = (d7 & 0xffff0000) | ((unsigned)d6 >> 16);

#pragma unroll
        for (int nt = 0; nt < 6; ++nt) {
            const unsigned short* bhp = bb + ((size_t)nt * 23 + ki) * 512 + lane * 8;
            const unsigned short* blp = bhp + (size_t)12 * 23 * 512;
            short8 bh = *(const short8*)bhp;
            short8 bl = *(const short8*)blp;
            acc[nt] = __builtin_amdgcn_mfma_f32_16x16x32_bf16(ah.v, bh, acc[nt], 0, 0, 0);
            acc[nt] = __builtin_amdgcn_mfma_f32_16x16x32_bf16(ah.v, bl, acc[nt], 0, 0, 0);
            acc[nt] = __builtin_amdgcn_mfma_f32_16x16x32_bf16(al.v, bh, acc[nt], 0, 0, 0);
        }
    }

    const int sbase = y0 * 48 + wv * 16 + quad * 4;
#pragma unroll
    for (int nt = 0; nt < 6; ++nt) {
        int oc = nb * 96 + nt * 16 + mcol;
        float bv = ob[oc];
        float* dst = iog + ((size_t)n * 192 + oc) * 1152 + sbase;
#pragma unroll
        for (int r = 0; r < 4; ++r) dst[r] = acc[nt][r] + bv;
    }
}

// ---------------- 1x1 q/k/v + mk/mv projections ----------------
__global__ __launch_bounds__(256) void k_qkv(
    const float* __restrict__ h, const float* __restrict__ m,
    const float* __restrict__ hw, const float* __restrict__ hb,
    const float* __restrict__ mw, const float* __restrict__ mb,
    float* __restrict__ qkv, float* __restrict__ mkv) {
    __shared__ float lw[512];
    __shared__ float lb[8];
    const int g = blockIdx.y;
    const int tid = threadIdx.x;
    const float* wsrc = (g < 6) ? (hw + g * 512) : (mw + (g - 6) * 512);
    const float* bsrc = (g < 6) ? (hb + g * 8) : (mb + (g - 6) * 8);
    for (int i = tid; i < 512; i += 256) lw[i] = wsrc[i];
    if (tid < 8) lb[tid] = bsrc[tid];
    __syncthreads();

    int idx = blockIdx.x * 256 + tid;
    int s = idx % SS;
    int n = idx / SS;
    int y = s / WW, x = s % WW;

    float reg[HD];
    if (g < 6) {
        const float* src = h + (size_t)n * HD * PHW + (y + 1) * PC + (x + 1);
#pragma unroll
        for (int ic = 0; ic < HD; ++ic) reg[ic] = src[ic * PHW];
    } else {
        const float* src = m + (size_t)n * HD * SS + s;
#pragma unroll
        for (int ic = 0; ic < HD; ++ic) reg[ic] = src[ic * SS];
    }

    float* dst = (g < 6) ? &qkv[((size_t)n * SS + s) * 48 + g * 8]
                         : &mkv[((size_t)n * SS + s) * 32 + (g - 6) * 8];
#pragma unroll
    for (int j = 0; j < 8; ++j) {
        const float* wr = &lw[j * HD];
        float a = lb[j];
#pragma unroll
        for (int ic = 0; ic < HD; ++ic) a += reg[ic] * wr[ic];
        dst[j] = a;
    }
}

#define LOAD16(dst, srcp) do {                       \
    float4 _a = ((const float4*)(srcp))[0];          \
    float4 _b = ((const float4*)(srcp))[1];          \
    float4 _c = ((const float4*)(srcp))[2];          \
    float4 _d = ((const float4*)(srcp))[3];          \
    dst[0]=_a.x; dst[1]=_a.y; dst[2]=_a.z; dst[3]=_a.w;   \
    dst[4]=_b.x; dst[5]=_b.y; dst[6]=_b.z; dst[7]=_b.w;   \
    dst[8]=_c.x; dst[9]=_c.y; dst[10]=_c.z; dst[11]=_c.w; \
    dst[12]=_d.x; dst[13]=_d.y; dst[14]=_d.z; dst[15]=_d.w; } while(0)

// ---------------- dual spatial attention + z 1x1 (r8-verbatim) ----------------
#define TSTRIDE 68
__global__ __launch_bounds__(256) void k_attn(
    const float* __restrict__ qkv, const float* __restrict__ mkv,
    const float* __restrict__ zw, const float* __restrict__ zb,
    float* __restrict__ Z)
{
    __shared__ __align__(16) float smem[144 * TSTRIDE];
    const int n = blockIdx.y;
    const int tid = threadIdx.x;
    const int rowthr = tid >> 4;
    const int part = tid & 15;
    const int s0 = blockIdx.x * 32 + rowthr * 2;

    float q0[16], q1[16];
    LOAD16(q0, &qkv[((size_t)n * SS + s0) * 48]);
    LOAD16(q1, &qkv[((size_t)n * SS + s0 + 1) * 48]);

    float lh0 = 0.f, lh1 = 0.f, lm0 = 0.f, lm1 = 0.f;
    float oh0[16], oh1[16], om0[16], om1[16];
#pragma unroll
    for (int j = 0; j < 16; ++j) { oh0[j] = 0.f; oh1[j] = 0.f; om0[j] = 0.f; om1[j] = 0.f; }

    const float4* qkv4 = (const float4*)qkv + (size_t)n * SS * 12;
    const float4* mkv4 = (const float4*)mkv + (size_t)n * SS * 8;

    for (int tile = 0; tile < 8; ++tile) {
        __syncthreads();
#pragma unroll
        for (int k = 0; k < 9; ++k) {
            int j = tid + 256 * k;
            int t_loc = j >> 4, f = j & 15;
            int t = tile * 144 + t_loc;
            float4 v;
            if (f < 8) v = qkv4[t * 12 + 4 + f];
            else       v = mkv4[t * 8 + (f - 8)];
            *(float4*)&smem[t_loc * TSTRIDE + f * 4] = v;
        }
        __syncthreads();

        const int t0 = part * 9;
        for (int tl = t0; tl < t0 + 9; ++tl) {
            const float* kvb = &smem[tl * TSTRIDE];
            float kk[16], vv[16];
            LOAD16(kk, kvb);
            float d0 = 0.f, d1 = 0.f;
#pragma unroll
            for (int j = 0; j < 16; ++j) { d0 += q0[j] * kk[j]; d1 += q1[j] * kk[j]; }
            float e0 = __expf(d0 * 0.25f), e1 = __expf(d1 * 0.25f);
            lh0 += e0; lh1 += e1;
            LOAD16(vv, kvb + 16);
#pragma unroll
            for (int j = 0; j < 16; ++j) { oh0[j] += e0 * vv[j]; oh1[j] += e1 * vv[j]; }
            LOAD16(kk, kvb + 32);
            float f0 = 0.f, f1 = 0.f;
#pragma unroll
            for (int j = 0; j < 16; ++j) { f0 += q0[j] * kk[j]; f1 += q1[j] * kk[j]; }
            float g0 = __expf(f0 * 0.25f), g1 = __expf(f1 * 0.25f);
            lm0 += g0; lm1 += g1;
            LOAD16(vv, kvb + 48);
#pragma unroll
            for (int j = 0; j < 16; ++j) { om0[j] += g0 * vv[j]; om1[j] += g1 * vv[j]; }
        }
    }

#pragma unroll
    for (int mask = 1; mask <= 8; mask <<= 1) {
        lh0 += __shfl_xor(lh0, mask, 16);
        lh1 += __shfl_xor(lh1, mask, 16);
        lm0 += __shfl_xor(lm0, mask, 16);
        lm1 += __shfl_xor(lm1, mask, 16);
#pragma unroll
        for (int j = 0; j < 16; ++j) {
            oh0[j] += __shfl_xor(oh0[j], mask, 16);
            oh1[j] += __shfl_xor(oh1[j], mask, 16);
            om0[j] += __shfl_xor(om0[j], mask, 16);
            om1[j] += __shfl_xor(om1[j], mask, 16);
        }
    }

    const int zc = part;
    const float* zr = &zw[zc * 32];
    float zrh[16], zrm[16];
    LOAD16(zrh, zr);
    LOAD16(zrm, zr + 16);
    float zbv = zb[zc];
    float ilh0 = 1.f / lh0, ilh1 = 1.f / lh1;
    float ilm0 = 1.f / lm0, ilm1 = 1.f / lm1;
    float a0 = zbv, a1 = zbv;
#pragma unroll
    for (int j = 0; j < 16; ++j) {
        a0 += zrh[j] * (oh0[j] * ilh0) + zrm[j] * (om0[j] * ilm0);
        a1 += zrh[j] * (oh1[j] * ilh1) + zrm[j] * (om1[j] * ilm1);
    }
    {
        int y0_ = s0 / WW, x0_ = s0 % WW;
        Z[((size_t)(n * DATT + zc) * PR + y0_ + 1) * PC + x0_ + 1] = a0;
        int y1_ = (s0 + 1) / WW, x1_ = (s0 + 1) % WW;
        Z[((size_t)(n * DATT + zc) * PR + y1_ + 1) * PC + x1_ + 1] = a1;
    }
}

// ---------------- SA memory gates (writes carry h = hB, padded) ----------------
__global__ void k_sa_gates(const float* __restrict__ iog, float* __restrict__ m,
                           float* __restrict__ h) {
    int i = blockIdx.x * blockDim.x + threadIdx.x;
    if (i >= NB * HD * SS) return;
    int s = i % SS;
    int ch = (i / SS) % HD;
    int n = i / (HD * SS);
    const float* ib = iog + (size_t)n * 3 * HD * SS;
    float si = ib[ch * SS + s];
    float sg = ib[(HD + ch) * SS + s];
    float so = ib[(2 * HD + ch) * SS + s];
    si = sigmoidf_(si);
    sg = tanhf(sg);
    float mn = si * sg + (1.f - si) * m[i];
    m[i] = mn;
    int y = s / WW, x = s % WW;
    h[((size_t)(n * HD + ch) * PR + (y + 1)) * PC + (x + 1)] = sigmoidf_(so) * mn;
}

// ---------------- out 1x1 (64->2) + next-step feed, fused ----------------
__global__ void k_out_feed(const float* __restrict__ h, const float* __restrict__ ow,
                           const float* __restrict__ ob, const float* __restrict__ x,
                           float* __restrict__ outbuf, float* __restrict__ feed, int t) {
    int idx = blockIdx.x * 256 + threadIdx.x;
    if (idx >= NB * SS) return;
    int s = idx % SS;
    int n = idx / SS;
    int y = s / WW, xx = s % WW;
    const float* src = h + (size_t)n * HD * PHW + (y + 1) * PC + (xx + 1);
    float o0 = ob[0], o1 = ob[1];
#pragma unroll
    for (int ic = 0; ic < HD; ++ic) {
        float r = src[ic * PHW];
        o0 += r * ow[ic];
        o1 += r * ow[HD + ic];
    }
    outbuf[(((size_t)n * TSTEPS + t) * NCOUT + 0) * SS + s] = o0;
    outbuf[(((size_t)n * TSTEPS + t) * NCOUT + 1) * SS + s] = o1;

    if (t + 1 < TSTEPS) {
        int t1 = t + 1;
        const float* xp = &x[(((size_t)(n * TSTEPS + t1) * HH + y) * WW + xx) * NCIN];
        float f0, f1, f2 = xp[2];
        if (t1 < INPUT_FRAMES) { f0 = xp[0]; f1 = xp[1]; }
        else { f0 = o0; f1 = o1; }
        size_t fb = ((size_t)(n * 3 + 0) * PR + y + 1) * PC + xx + 1;
        feed[fb] = f0;
        feed[fb + PHW] = f1;
        feed[fb + 2 * (size_t)PHW] = f2;
    }
}

// ---------------- nino prediction ----------------
__global__ void k_nino(const float* __restrict__ outbuf, float* __restrict__ pred) {
    int tidx = threadIdx.x;
    if (tidx >= 16 * 24) return;
    int j = tidx % 24;
    int n = tidx / 24;
    float acc = 0.f;
    for (int f = j; f < j + 3; ++f) {
        int t = 11 + f;
        const float* p = &outbuf[(((size_t)n * TSTEPS + t) * NCOUT + 0) * SS];
        float sloc = 0.f;
        for (int y = 10; y <= 12; ++y)
            for (int x = 19; x <= 29; ++x)
                sloc += p[y * WW + x];
        acc += sloc * (1.f / 33.f);
    }
    pred[n * 24 + j] = acc * (1.f / 3.f);
}

extern "C" void kernel_launch(void* const* d_in, const int* in_sizes, int n_in,
                              void* d_out, int out_size, void* d_ws, size_t ws_size,
                              hipStream_t stream) {
    const float* x      = (const float*)d_in[0];
    const float* conv_w = (const float*)d_in[1];
    const float* conv_b = (const float*)d_in[2];
    const float* h_w    = (const float*)d_in[3];
    const float* h_b    = (const float*)d_in[4];
    const float* m_w    = (const float*)d_in[5];
    const float* m_b    = (const float*)d_in[6];
    const float* z_w    = (const float*)d_in[7];
    const float* z_b    = (const float*)d_in[8];
    const float* o_w    = (const float*)d_in[9];
    const float* o_b    = (const float*)d_in[10];
    const float* out_w  = (const float*)d_in[11];
    const float* out_b  = (const float*)d_in[12];

    float* ws   = (float*)d_ws;
    float* hA   = ws + OFF_H;
    float* c    = ws + OFF_C;
    float* m    = ws + OFF_M;
    float* feed = ws + OFF_FEED;
    float* Zb   = ws + OFF_Z;
    float* qkv  = ws + OFF_QKV;
    float* mkv  = ws + OFF_MKV;
    float* hB   = ws + OFF_HB;
    float* iog  = ws + OFF_IOG;
    unsigned short* bf2 = (unsigned short*)(ws + OFF_BF2);
    unsigned short* bf  = (unsigned short*)(ws + OFF_BF);
    float* outp = (float*)d_out;

    k_zero<<<4058, 256, 0, stream>>>(ws, 1038688);                 // hA,c,m,feed,Z
    k_zero<<<1352, 256, 0, stream>>>(ws + OFF_HB, 346112);         // hB
    k_prep_bf2<<<1344, 256, 0, stream>>>(conv_w, bf2);
    k_prep_bf<<<1104, 256, 0, stream>>>(o_w, bf);
    k_feed0<<<216, 256, 0, stream>>>(x, feed);

    for (int t = 0; t < TSTEPS; ++t) {
        k_conv_lstm_mfma<<<dim3(24, 2, 16), 192, 0, stream>>>(feed, hB, bf2, conv_b, c, hA);
        k_qkv<<<dim3(72, 10), 256, 0, stream>>>(hA, m, h_w, h_b, m_w, m_b, qkv, mkv);
        k_attn<<<dim3(36, 16), 256, 0, stream>>>(qkv, mkv, z_w, z_b, Zb);
        k_conv_mfma<<<dim3(24, 2, 16), 192, 0, stream>>>(Zb, hA, bf, o_b, iog);
        k_sa_gates<<<4608, 256, 0, stream>>>(iog, m, hB);
        k_out_feed<<<72, 256, 0, stream>>>(hB, out_w, out_b, x, outp, feed, t);
    }
    k_nino<<<1, 384, 0, stream>>>(outp, outp + (size_t)NB * TSTEPS * NCOUT * SS);
}